// Round 15
// baseline (4124.961 us; speedup 1.0000x reference)
//
#include <hip/hip_runtime.h>
#include <math.h>

#define KNN 20
#define NPTS 4096
#define NB 8

__device__ __forceinline__ bool lexless(float d1, int i1, float d2, int i2) {
    return d1 < d2 || (d1 == d2 && i1 < i2);
}

// ---------------------------------------------------------------- concat x|pos + squared norm (fused)
__global__ __launch_bounds__(256) void concat_norm_kernel(const float* __restrict__ x,
                                                          const float* __restrict__ pos,
                                                          float* __restrict__ f0,
                                                          float* __restrict__ nrm, int total) {
    int p = blockIdx.x * 256 + threadIdx.x;
    if (p < total) {
        float v0 = x[(size_t)p*3 + 0], v1 = x[(size_t)p*3 + 1], v2 = x[(size_t)p*3 + 2];
        float v3 = pos[(size_t)p*3 + 0], v4 = pos[(size_t)p*3 + 1], v5 = pos[(size_t)p*3 + 2];
        f0[(size_t)p*6 + 0] = v0; f0[(size_t)p*6 + 1] = v1; f0[(size_t)p*6 + 2] = v2;
        f0[(size_t)p*6 + 3] = v3; f0[(size_t)p*6 + 4] = v4; f0[(size_t)p*6 + 5] = v5;
        float s = 0.f;
        s = fmaf(v0, v0, s); s = fmaf(v1, v1, s); s = fmaf(v2, v2, s);
        s = fmaf(v3, v3, s); s = fmaf(v4, v4, s); s = fmaf(v5, v5, s);
        nrm[p] = s;
    }
}

// ---------------------------------------------------------------- squared norms
template<int C>
__global__ __launch_bounds__(256) void norm_kernel(const float* __restrict__ f, int ldf,
                                                   float* __restrict__ norms, int total) {
    int p = blockIdx.x * 256 + threadIdx.x;
    if (p >= total) return;
    const float* fp = f + (size_t)p * ldf;
    float s = 0.f;
    if constexpr ((C & 3) == 0) {
#pragma unroll
        for (int k = 0; k < C; k += 4) {
            float4 v = *(const float4*)(fp + k);
            s = fmaf(v.x, v.x, s); s = fmaf(v.y, v.y, s);
            s = fmaf(v.z, v.z, s); s = fmaf(v.w, v.w, s);
        }
    } else {
#pragma unroll
        for (int k = 0; k < C; ++k) s = fmaf(fp[k], fp[k], s);
    }
    norms[p] = s;
}

// ---- sortable-key top-k machinery -------------------------------------------
// key = (sign-fixed float bits << 32) | idx ; u64 '<' == lexless((d,idx)).
// Internal names chosen to avoid macro variable capture (round-3 lesson).
#define KCHAIN(ck_) do {                                                 \
    unsigned long long kc = (ck_);                                       \
    _Pragma("unroll")                                                    \
    for (int t = 0; t < KNN; ++t) {                                      \
        bool sw = kc < bk[t];                                            \
        unsigned long long nn = sw ? kc : bk[t];                         \
        unsigned long long oo = sw ? bk[t] : kc;                         \
        bk[t] = nn; kc = oo;                                             \
    }                                                                    \
} while (0)

#define PACKK(dv_, jv_, out_) do {                                       \
    unsigned pu = __float_as_uint(dv_);                                  \
    pu = (pu == 0x80000000u) ? 0u : pu;     /* -0 -> +0 */               \
    pu ^= (unsigned)((int)pu >> 31) | 0x80000000u;                       \
    (out_) = ((unsigned long long)pu << 32) | (unsigned)(jv_);           \
} while (0)

// Fast-path push: raw float compare vs cached threshold (superset of the exact
// key test; the chain rejects exactly at flush time). Pending depth 6:
// cadence-4 checks of cnt>=3 -> residual<=2, +4 new <= 6 (holds ACROSS tiles).
#define PUSHF(dv_, jg_) do {                                             \
    if ((dv_) <= thr) {                                                  \
        pd5 = pd4; pj5 = pj4; pd4 = pd3; pj4 = pj3;                      \
        pd3 = pd2; pj3 = pj2; pd2 = pd1; pj2 = pj1;                      \
        pd1 = pd0; pj1 = pj0; pd0 = (dv_); pj0 = (jg_); ++cnt;           \
    }                                                                    \
} while (0)

// Flush: exact u64-key chain insert of pending items, then tighten own float
// threshold from bk[19] and share it per-query via LDS atomicMin.
#define FLUSHF() do {                                                    \
    if (cnt > 0) { unsigned long long k0_; PACKK(pd0, pj0, k0_); KCHAIN(k0_); } \
    if (cnt > 1) { unsigned long long k1_; PACKK(pd1, pj1, k1_); KCHAIN(k1_); } \
    if (cnt > 2) { unsigned long long k2_; PACKK(pd2, pj2, k2_); KCHAIN(k2_); } \
    if (cnt > 3) { unsigned long long k3_; PACKK(pd3, pj3, k3_); KCHAIN(k3_); } \
    if (cnt > 4) { unsigned long long k4_; PACKK(pd4, pj4, k4_); KCHAIN(k4_); } \
    if (cnt > 5) { unsigned long long k5_; PACKK(pd5, pj5, k5_); KCHAIN(k5_); } \
    cnt = 0;                                                             \
    unsigned hu_ = (unsigned)(bk[KNN - 1] >> 32);                        \
    atomicMin(&thrQ[q], hu_);                                            \
    hu_ = (hu_ & 0x80000000u) ? (hu_ ^ 0x80000000u) : ~hu_;              \
    thr = __uint_as_float(hu_);                                          \
} while (0)

#define KMERGE(ptr_) do {                                                \
    const unsigned long long* mp = (ptr_);                               \
    _Pragma("unroll 1")                                                  \
    for (int tm = 0; tm < KNN; ++tm) {                                   \
        unsigned long long mk = mp[tm];                                  \
        if (mk >= bk[KNN - 1]) break;                                    \
        KCHAIN(mk);                                                      \
    }                                                                    \
} while (0)

// sentinel key = pack(+INF, 0xFFFFFFFF)
#define KSENTINEL 0xFF800000FFFFFFFFULL

// ---------------------------------------------------------------- fused tiled kNN (C=64)
// Query-split; 128-thread block owns 32 queries; grid = TOT/32 = 1024 blocks.
// R7 structure. R15: per-tile forced drain REMOVED (R9 addition) — once the
// threshold tightens it issued a >=105-inst wave-wide flush every tile for
// ~1 pending item; cadence-4 cnt>=3 ballot alone bounds pending at 6 across
// tiles, final drain before merge kept.
template<int C>
__global__ __launch_bounds__(128, 2) void knn_tile_kernel(const float* __restrict__ f, int ldf,
                                                          const float* __restrict__ norms,
                                                          int* __restrict__ idx) {
    const int qb    = blockIdx.x * 32;
    const int b     = qb >> 12;
    const int qloc0 = qb & (NPTS - 1);
    const int tid   = threadIdx.x;
    const int q     = tid & 31;            // query (scan/merge role)
    const int sub   = tid >> 5;            // 0..3 candidate sub-range
    const int tx    = tid & 15;            // candidate quad (GEMM role)
    const int ty    = tid >> 4;            // query quad 0..7 (GEMM role)

    union __align__(16) SM {
        struct {
            float Qs[C][32];
            float Cs[C][64];
            float Ds[32][68];              // row stride 272 B (16B-aligned)
        } a;
        unsigned long long md[32][2 * KNN + 1];   // merge lists (padded stride)
    };
    __shared__ SM sm;
    __shared__ unsigned thrQ[32];          // per-query shared packed threshold

    const float* fb = f + (size_t)b * NPTS * ldf;
    const float* nb = norms + (size_t)b * NPTS;

    if (tid < 32) thrQ[tid] = 0xFFFFFFFFu;

    // ---- stage query tile Qs[k][m] (once)
    if constexpr ((C & 15) == 0) {
        int m = tid >> 2, ko = (tid & 3) * 4;
        const float* src = fb + (size_t)(qloc0 + m) * ldf;
#pragma unroll
        for (int k4 = ko; k4 < C; k4 += 16) {
            float4 v = *(const float4*)(src + k4);
            sm.a.Qs[k4 + 0][m] = v.x; sm.a.Qs[k4 + 1][m] = v.y;
            sm.a.Qs[k4 + 2][m] = v.z; sm.a.Qs[k4 + 3][m] = v.w;
        }
    } else {
        for (int e = tid; e < C * 32; e += 128) {
            int k = e >> 5, m = e & 31;
            sm.a.Qs[k][m] = fb[(size_t)(qloc0 + m) * ldf + k];
        }
    }

    const float4 qnv = *(const float4*)(nb + qloc0 + ty * 4);
    const float qnr[4] = {qnv.x, qnv.y, qnv.z, qnv.w};

    unsigned long long bk[KNN];
#pragma unroll
    for (int t = 0; t < KNN; ++t) bk[t] = KSENTINEL;
    float thr = INFINITY;
    float pd0 = 0.f, pd1 = 0.f, pd2 = 0.f, pd3 = 0.f, pd4 = 0.f, pd5 = 0.f;
    int   pj0 = 0, pj1 = 0, pj2 = 0, pj3 = 0, pj4 = 0, pj5 = 0;
    int   cnt = 0;

    auto stageC = [&](int j0) {
        if constexpr ((C & 7) == 0) {
            int jj = tid >> 1, ko = (tid & 1) * 4;
            const float* src = fb + (size_t)(j0 + jj) * ldf;
#pragma unroll
            for (int k4 = ko; k4 < C; k4 += 8) {
                float4 v = *(const float4*)(src + k4);
                sm.a.Cs[k4 + 0][jj] = v.x; sm.a.Cs[k4 + 1][jj] = v.y;
                sm.a.Cs[k4 + 2][jj] = v.z; sm.a.Cs[k4 + 3][jj] = v.w;
            }
        } else {
            for (int e = tid; e < C * 64; e += 128) {
                int k = e >> 6, j = e & 63;
                sm.a.Cs[k][j] = fb[(size_t)(j0 + j) * ldf + k];
            }
        }
    };

    auto gemmT = [&](int j0) {
        float acc[4][4] = {};
#pragma unroll 8
        for (int kk = 0; kk < C; ++kk) {
            float4 av = *(const float4*)&sm.a.Qs[kk][ty * 4];
            float4 bv = *(const float4*)&sm.a.Cs[kk][tx * 4];
            float a[4] = {av.x, av.y, av.z, av.w};
            float bb[4] = {bv.x, bv.y, bv.z, bv.w};
#pragma unroll
            for (int i = 0; i < 4; ++i)
#pragma unroll
                for (int j = 0; j < 4; ++j) acc[i][j] = fmaf(a[i], bb[j], acc[i][j]);
        }
        const float4 cnv = *(const float4*)(nb + j0 + tx * 4);
#pragma unroll
        for (int i = 0; i < 4; ++i) {
            float4 o;
            o.x = fmaf(-2.0f, acc[i][0], qnr[i] + cnv.x);
            o.y = fmaf(-2.0f, acc[i][1], qnr[i] + cnv.y);
            o.z = fmaf(-2.0f, acc[i][2], qnr[i] + cnv.z);
            o.w = fmaf(-2.0f, acc[i][3], qnr[i] + cnv.w);
            *(float4*)&sm.a.Ds[ty * 4 + i][tx * 4] = o;
        }
    };

    auto scanT = [&](int j0) {
        {
            unsigned su = thrQ[q];
            unsigned hu = (su & 0x80000000u) ? (su ^ 0x80000000u) : ~su;
            thr = fminf(thr, __uint_as_float(hu));
        }
        const int jb = sub * 16;
        const float4 v0 = *(const float4*)&sm.a.Ds[q][jb + 0];
        const float4 v1 = *(const float4*)&sm.a.Ds[q][jb + 4];
        const float4 v2 = *(const float4*)&sm.a.Ds[q][jb + 8];
        const float4 v3 = *(const float4*)&sm.a.Ds[q][jb + 12];
        const int jg = j0 + jb;
        PUSHF(v0.x, jg + 0);  PUSHF(v0.y, jg + 1);
        PUSHF(v0.z, jg + 2);  PUSHF(v0.w, jg + 3);  if (__any(cnt >= 3)) FLUSHF();
        PUSHF(v1.x, jg + 4);  PUSHF(v1.y, jg + 5);
        PUSHF(v1.z, jg + 6);  PUSHF(v1.w, jg + 7);  if (__any(cnt >= 3)) FLUSHF();
        PUSHF(v2.x, jg + 8);  PUSHF(v2.y, jg + 9);
        PUSHF(v2.z, jg + 10); PUSHF(v2.w, jg + 11); if (__any(cnt >= 3)) FLUSHF();
        PUSHF(v3.x, jg + 12); PUSHF(v3.y, jg + 13);
        PUSHF(v3.z, jg + 14); PUSHF(v3.w, jg + 15); if (__any(cnt >= 3)) FLUSHF();
        // no per-tile drain (R15): pending persists across tiles, depth <= 6
    };

    // ---- pipelined main loop: 2 barriers per tile
    stageC(0);
    __syncthreads();
    gemmT(0);
    __syncthreads();
#pragma unroll 1
    for (int t = 1; t < NPTS / 64; ++t) {
        stageC(t * 64);          // writes Cs (gemm(t-1) done reading it)
        scanT((t - 1) * 64);     // reads Ds(t-1)
        __syncthreads();
        gemmT(t * 64);           // reads Cs(t), overwrites Ds
        __syncthreads();
    }
    scanT(NPTS - 64);
    if (__any(cnt > 0)) FLUSHF();   // final drain before merge

    // ---- hierarchical 4 -> 1 merge of sorted lists (per query q)
    __syncthreads();   // all Ds reads done; alias md over a.*
    if (sub >= 2) {
#pragma unroll
        for (int t = 0; t < KNN; ++t) sm.md[q][(sub - 2) * KNN + t] = bk[t];
    }
    __syncthreads();
    if (sub < 2) KMERGE(&sm.md[q][sub * KNN]);
    __syncthreads();
    if (sub == 1) {
#pragma unroll
        for (int t = 0; t < KNN; ++t) sm.md[q][t] = bk[t];
    }
    __syncthreads();
    if (sub == 0) {
        KMERGE(&sm.md[q][0]);
        int* op = idx + (size_t)(qb + q) * KNN;
#pragma unroll
        for (int t = 0; t < KNN; ++t) op[t] = (int)bk[t];
    }
}

// ---------------------------------------------------------------- specialized kNN for C=6
// (128, 2) — NOT (128, 4): R11 lesson (64-VGPR cap spilled bk[20]).
__global__ __launch_bounds__(128, 2) void knn6_kernel(const float* __restrict__ f,
                                                      const float* __restrict__ norms,
                                                      int* __restrict__ idx) {
    const int qb    = blockIdx.x * 32;
    const int b     = qb >> 12;
    const int qloc0 = qb & (NPTS - 1);
    const int tid   = threadIdx.x;
    const int q     = tid & 31;
    const int sub   = tid >> 5;

    __shared__ __align__(16) float Cs[2][64][8];
    __shared__ unsigned long long md[32][2 * KNN + 1];
    __shared__ unsigned thrQ[32];

    const float* fb = f + (size_t)b * NPTS * 6;
    const float* nb = norms + (size_t)b * NPTS;

    if (tid < 32) thrQ[tid] = 0xFFFFFFFFu;

    float fir[6];
    {
        const float* qsrc = fb + (size_t)(qloc0 + q) * 6;
#pragma unroll
        for (int k = 0; k < 6; ++k) fir[k] = qsrc[k];
    }
    const float qn = nb[qloc0 + q];

    unsigned long long bk[KNN];
#pragma unroll
    for (int t = 0; t < KNN; ++t) bk[t] = KSENTINEL;
    float thr = INFINITY;
    float pd0 = 0.f, pd1 = 0.f, pd2 = 0.f, pd3 = 0.f, pd4 = 0.f, pd5 = 0.f;
    int   pj0 = 0, pj1 = 0, pj2 = 0, pj3 = 0, pj4 = 0, pj5 = 0;
    int   cnt = 0;

    auto stage6 = [&](int j0, int s) {
#pragma unroll
        for (int e = tid; e < 512; e += 128) {
            int j = e >> 3, k = e & 7;
            float v = 0.f;
            if (k < 6)       v = fb[(size_t)(j0 + j) * 6 + k];
            else if (k == 6) v = nb[j0 + j];
            Cs[s][j][k] = v;
        }
    };

    auto scan6 = [&](int j0, int s) {
        {
            unsigned su = thrQ[q];
            unsigned hu = (su & 0x80000000u) ? (su ^ 0x80000000u) : ~su;
            thr = fminf(thr, __uint_as_float(hu));
        }
        const int jb = sub * 16;
#pragma unroll
        for (int jj = 0; jj < 16; ++jj) {
            const float4 c0 = *(const float4*)&Cs[s][jb + jj][0];
            const float4 c1 = *(const float4*)&Cs[s][jb + jj][4];
            float dot = 0.f;
            dot = fmaf(fir[0], c0.x, dot);
            dot = fmaf(fir[1], c0.y, dot);
            dot = fmaf(fir[2], c0.z, dot);
            dot = fmaf(fir[3], c0.w, dot);
            dot = fmaf(fir[4], c1.x, dot);
            dot = fmaf(fir[5], c1.y, dot);
            float d = fmaf(-2.0f, dot, qn + c1.z);
            PUSHF(d, j0 + jb + jj);
            if ((jj & 3) == 3) { if (__any(cnt >= 3)) FLUSHF(); }
        }
        // no per-tile drain (R15)
    };

    stage6(0, 0);
    __syncthreads();
#pragma unroll 1
    for (int t = 0; t < NPTS / 64; ++t) {
        const int cur = t & 1;
        if (t + 1 < NPTS / 64) stage6((t + 1) * 64, cur ^ 1);
        scan6(t * 64, cur);
        __syncthreads();
    }
    if (__any(cnt > 0)) FLUSHF();   // final drain

    if (sub >= 2) {
#pragma unroll
        for (int t = 0; t < KNN; ++t) md[q][(sub - 2) * KNN + t] = bk[t];
    }
    __syncthreads();
    if (sub < 2) KMERGE(&md[q][sub * KNN]);
    __syncthreads();
    if (sub == 1) {
#pragma unroll
        for (int t = 0; t < KNN; ++t) md[q][t] = bk[t];
    }
    __syncthreads();
    if (sub == 0) {
        KMERGE(&md[q][0]);
        int* op = idx + (size_t)(qb + q) * KNN;
#pragma unroll
        for (int t = 0; t < KNN; ++t) op[t] = (int)bk[t];
    }
}

// ---------------------------------------------------------------- H|G for conv1 (C=6): tiny K=6 dense layer
__global__ __launch_bounds__(256) void hg6_kernel(const float* __restrict__ f0,
                                                  const float* __restrict__ W1,
                                                  const float* __restrict__ b1,
                                                  float* __restrict__ GH, int total) {
    int t = blockIdx.x * 256 + threadIdx.x;
    if (t >= total * 128) return;
    int p  = t >> 7;
    int cc = t & 127;
    int c  = cc & 63;
    bool isG = cc >= 64;
    const float* fp = f0 + (size_t)p * 6;
    const float* Wb = W1 + (isG ? 6 * 64 : 0);
    float acc = isG ? 0.f : b1[c];
#pragma unroll
    for (int k = 0; k < 6; ++k) acc = fmaf(fp[k], Wb[k * 64 + c], acc);
    GH[(size_t)p * 128 + cc] = acc;
}

// ---------------------------------------------------------------- repack W1 -> [64 x 128] (W1a | W1b), bias' = (b1 | 0)
__global__ __launch_bounds__(256) void repack_w1_kernel(const float* __restrict__ W1,
                                                        const float* __restrict__ b1,
                                                        float* __restrict__ Wp,
                                                        float* __restrict__ bp) {
    int t = blockIdx.x * 256 + threadIdx.x;
    if (t < 64 * 64) {
        int k = t >> 6, c = t & 63;
        Wp[k * 128 + c]      = W1[k * 64 + c];          // W1a
        Wp[k * 128 + 64 + c] = W1[(64 + k) * 64 + c];   // W1b
    }
    if (t < 128) bp[t] = (t < 64) ? b1[t] : 0.f;
}

// ---------------------------------------------------------------- factored EdgeConv: layer1 = adds on precomputed GH
__global__ __launch_bounds__(64) void edgeconv_fact_kernel(
    const float* __restrict__ GH,          // [TOT x 128]: [H | G]
    const int* __restrict__ idx,
    const float* __restrict__ g,  const float* __restrict__ be,
    const float* __restrict__ W2, const float* __restrict__ b2,
    float* __restrict__ out, int ldo) {
    const int p = blockIdx.x;
    const int b = p >> 12;
    const int c = threadIdx.x;   // channel 0..63
    __shared__ __align__(16) float h1_s[KNN][64];
    __shared__ int nidx[KNN];
    if (c < KNN) nidx[c] = idx[(size_t)p * KNN + c];
    const float H = GH[(size_t)p * 128 + c];
    const float G = GH[(size_t)p * 128 + 64 + c];
    const float hb = H - G;                       // (H_i - G_i)
    const float bn_s = (float)(1.0 / sqrt(1.0 + 1e-5));
    const float bnscale = g[c] * bn_s;
    const float bec = be[c];
    const float* GHb = GH + (size_t)b * NPTS * 128 + 64;  // G part, batch base
    __syncthreads();
#pragma unroll
    for (int j = 0; j < KNN; ++j) {
        float gj = GHb[(size_t)nidx[j] * 128 + c];
        h1_s[j][c] = fmaxf(fmaf(hb + gj, bnscale, bec), 0.f);
    }
    __syncthreads();

    float acc2[KNN];
    float b2c = b2[c];
#pragma unroll
    for (int j = 0; j < KNN; ++j) acc2[j] = b2c;
#pragma unroll
    for (int k = 0; k < 64; k += 4) {
        float w0 = W2[(k + 0) * 64 + c];
        float w1 = W2[(k + 1) * 64 + c];
        float w2 = W2[(k + 2) * 64 + c];
        float w3 = W2[(k + 3) * 64 + c];
#pragma unroll
        for (int j = 0; j < KNN; ++j) {
            float4 v = *(const float4*)&h1_s[j][k];
            acc2[j] = fmaf(v.x, w0, acc2[j]);
            acc2[j] = fmaf(v.y, w1, acc2[j]);
            acc2[j] = fmaf(v.z, w2, acc2[j]);
            acc2[j] = fmaf(v.w, w3, acc2[j]);
        }
    }
    float m = acc2[0];
#pragma unroll
    for (int j = 1; j < KNN; ++j) m = fmaxf(m, acc2[j]);
    out[(size_t)p * ldo + c] = m;
}

// ---------------------------------------------------------------- tiled fp32 GEMM: C = act(A@W + b)
// 128x128x16 tile, 256 threads, 8x8 micro-tile, double-buffered staging
// (R15): prefetch tile t+1 to registers under compute of t, 1 barrier/K-step.
template<bool RELU>
__global__ __launch_bounds__(256, 2) void gemm_kernel(
    const float* __restrict__ A, int lda,
    const float* __restrict__ W,          // [K, N] row-major
    const float* __restrict__ bias,
    float* __restrict__ Cc, int ldc,
    int N, int K) {
    __shared__ __align__(16) float As[2][16][128 + 4];
    __shared__ __align__(16) float Bs[2][16][128 + 4];
    const int bm = blockIdx.y * 128;
    const int bn = blockIdx.x * 128;
    const int tid = threadIdx.x;
    const int tx = tid & 15, ty = tid >> 4;
    const int r  = tid >> 2, kq = (tid & 3) * 4;    // A-staging role
    const int kw = tid >> 4, n8 = (tid & 15) * 8;   // W-staging role
    const int nk = K / 16;
    float acc[8][8] = {};
    {   // prologue: stage tile 0 into buffer 0
        float4 a0 = *(const float4*)(A + (size_t)(bm + r) * lda + kq);
        float4 a1 = *(const float4*)(A + (size_t)(bm + r + 64) * lda + kq);
        As[0][kq + 0][r] = a0.x; As[0][kq + 1][r] = a0.y;
        As[0][kq + 2][r] = a0.z; As[0][kq + 3][r] = a0.w;
        As[0][kq + 0][r + 64] = a1.x; As[0][kq + 1][r + 64] = a1.y;
        As[0][kq + 2][r + 64] = a1.z; As[0][kq + 3][r + 64] = a1.w;
        float4 w0 = *(const float4*)(W + (size_t)kw * N + bn + n8);
        float4 w1 = *(const float4*)(W + (size_t)kw * N + bn + n8 + 4);
        *(float4*)&Bs[0][kw][n8] = w0;
        *(float4*)&Bs[0][kw][n8 + 4] = w1;
    }
    __syncthreads();
#pragma unroll 1
    for (int t = 0; t < nk; ++t) {
        const int cur = t & 1;
        float4 pa0, pa1, pw0, pw1;
        const bool more = (t + 1 < nk);
        if (more) {   // issue next-tile global loads; latency hides under compute
            int k0 = (t + 1) * 16;
            pa0 = *(const float4*)(A + (size_t)(bm + r) * lda + k0 + kq);
            pa1 = *(const float4*)(A + (size_t)(bm + r + 64) * lda + k0 + kq);
            pw0 = *(const float4*)(W + (size_t)(k0 + kw) * N + bn + n8);
            pw1 = *(const float4*)(W + (size_t)(k0 + kw) * N + bn + n8 + 4);
        }
#pragma unroll
        for (int kk = 0; kk < 16; ++kk) {
            float4 a0 = *(const float4*)&As[cur][kk][ty * 8];
            float4 a1 = *(const float4*)&As[cur][kk][ty * 8 + 4];
            float4 b0 = *(const float4*)&Bs[cur][kk][tx * 8];
            float4 b1 = *(const float4*)&Bs[cur][kk][tx * 8 + 4];
            float a[8] = {a0.x, a0.y, a0.z, a0.w, a1.x, a1.y, a1.z, a1.w};
            float bb[8] = {b0.x, b0.y, b0.z, b0.w, b1.x, b1.y, b1.z, b1.w};
#pragma unroll
            for (int i = 0; i < 8; ++i)
#pragma unroll
                for (int j = 0; j < 8; ++j) acc[i][j] = fmaf(a[i], bb[j], acc[i][j]);
        }
        if (more) {   // write prefetched tile to the other buffer (no readers there)
            const int nxt = cur ^ 1;
            As[nxt][kq + 0][r] = pa0.x; As[nxt][kq + 1][r] = pa0.y;
            As[nxt][kq + 2][r] = pa0.z; As[nxt][kq + 3][r] = pa0.w;
            As[nxt][kq + 0][r + 64] = pa1.x; As[nxt][kq + 1][r + 64] = pa1.y;
            As[nxt][kq + 2][r + 64] = pa1.z; As[nxt][kq + 3][r + 64] = pa1.w;
            *(float4*)&Bs[nxt][kw][n8] = pw0;
            *(float4*)&Bs[nxt][kw][n8 + 4] = pw1;
        }
        __syncthreads();
    }
    const float4 bi0 = *(const float4*)(bias + bn + tx * 8);
    const float4 bi1 = *(const float4*)(bias + bn + tx * 8 + 4);
    const float bb[8] = {bi0.x, bi0.y, bi0.z, bi0.w, bi1.x, bi1.y, bi1.z, bi1.w};
#pragma unroll
    for (int i = 0; i < 8; ++i) {
        int m = bm + ty * 8 + i;
        float4 o0, o1;
        o0.x = acc[i][0] + bb[0]; o0.y = acc[i][1] + bb[1];
        o0.z = acc[i][2] + bb[2]; o0.w = acc[i][3] + bb[3];
        o1.x = acc[i][4] + bb[4]; o1.y = acc[i][5] + bb[5];
        o1.z = acc[i][6] + bb[6]; o1.w = acc[i][7] + bb[7];
        if (RELU) {
            o0.x = fmaxf(o0.x, 0.f); o0.y = fmaxf(o0.y, 0.f);
            o0.z = fmaxf(o0.z, 0.f); o0.w = fmaxf(o0.w, 0.f);
            o1.x = fmaxf(o1.x, 0.f); o1.y = fmaxf(o1.y, 0.f);
            o1.z = fmaxf(o1.z, 0.f); o1.w = fmaxf(o1.w, 0.f);
        }
        *(float4*)(Cc + (size_t)m * ldc + bn + tx * 8) = o0;
        *(float4*)(Cc + (size_t)m * ldc + bn + tx * 8 + 4) = o1;
    }
}

// ---------------------------------------------------------------- final layer (K=128 -> 40) + log_softmax
// 256 threads = 4 waves = 4 points; W4 + h-rows staged in LDS.
__global__ __launch_bounds__(256) void head_kernel(const float* __restrict__ h3,
                                                   const float* __restrict__ W4,
                                                   const float* __restrict__ b4,
                                                   float* __restrict__ out) {
    __shared__ float W4s[128 * 40];
    __shared__ float hps[4][128];
    const int tid  = threadIdx.x;
    const int w    = tid >> 6;
    const int lane = tid & 63;
    const int p    = blockIdx.x * 4 + w;     // chunk-local point
    for (int e = tid; e < 128 * 40; e += 256) W4s[e] = W4[e];
    if (lane < 32)
        *(float4*)&hps[w][lane * 4] = *(const float4*)(h3 + (size_t)p * 128 + lane * 4);
    __syncthreads();
    float v = -INFINITY;
    if (lane < 40) {
        float acc = b4[lane];
#pragma unroll
        for (int k = 0; k < 128; ++k) acc = fmaf(hps[w][k], W4s[k * 40 + lane], acc);
        v = acc;
    }
    float mx = v;
#pragma unroll
    for (int s = 1; s < 64; s <<= 1) mx = fmaxf(mx, __shfl_xor(mx, s));
    float e = (lane < 40) ? expf(v - mx) : 0.0f;
    float se = e;
#pragma unroll
    for (int s = 1; s < 64; s <<= 1) se += __shfl_xor(se, s);
    if (lane < 40) out[(size_t)p * 40 + lane] = v - mx - logf(se);
}

// ----------------------------------------------------------------
extern "C" void kernel_launch(void* const* d_in, const int* in_sizes, int n_in,
                              void* d_out, int out_size, void* d_ws, size_t ws_size,
                              hipStream_t stream) {
    (void)in_sizes; (void)n_in; (void)out_size;
    const float* x     = (const float*)d_in[0];
    const float* pos   = (const float*)d_in[1];
    const float* c1_W1 = (const float*)d_in[2];
    const float* c1_b1 = (const float*)d_in[3];
    const float* c1_g  = (const float*)d_in[4];
    const float* c1_be = (const float*)d_in[5];
    const float* c1_W2 = (const float*)d_in[6];
    const float* c1_b2 = (const float*)d_in[7];
    const float* c2_W1 = (const float*)d_in[8];
    const float* c2_b1 = (const float*)d_in[9];
    const float* c2_g  = (const float*)d_in[10];
    const float* c2_be = (const float*)d_in[11];
    const float* c2_W2 = (const float*)d_in[12];
    const float* c2_b2 = (const float*)d_in[13];
    const float* c3_W1 = (const float*)d_in[14];
    const float* c3_b1 = (const float*)d_in[15];
    const float* c3_g  = (const float*)d_in[16];
    const float* c3_be = (const float*)d_in[17];
    const float* c3_W2 = (const float*)d_in[18];
    const float* c3_b2 = (const float*)d_in[19];
    const float* m_W1  = (const float*)d_in[20];
    const float* m_b1  = (const float*)d_in[21];
    const float* m_W2  = (const float*)d_in[22];
    const float* m_b2  = (const float*)d_in[23];
    const float* m_W3  = (const float*)d_in[24];
    const float* m_b3  = (const float*)d_in[25];
    const float* m_W4  = (const float*)d_in[26];
    const float* m_b4  = (const float*)d_in[27];
    float* out = (float*)d_out;

    const int TOT = NB * NPTS;  // 32768

    // workspace layout (floats):
    float* ws   = (float*)d_ws;
    float* f0   = ws;                              // 196608
    int*   idxb = (int*)(ws + 196608);             // 655360 ints
    float* feat = ws + 196608 + 655360;            // 6291456  [32768 x 192]

    const size_t basef  = 196608 + 655360 + 6291456;
    const size_t availf = ws_size / 4;
    int MC = 4096;
    if (availf >= basef + (size_t)32768 * 1408) MC = 32768;
    else if (availf >= basef + (size_t)16384 * 1408) MC = 16384;
    else if (availf >= basef + (size_t)8192 * 1408) MC = 8192;

    float* h1   = feat + 6291456;                  // [MC x 1024]
    float* h2   = h1 + (size_t)MC * 1024;          // [MC x 256]
    float* h3   = h2 + (size_t)MC * 256;           // [MC x 128]
    // conv-phase scratch (MLP region is dead then). Region size >= 5.77M floats.
    float* nrm  = h1;                              // 32768 floats
    float* GH   = h1 + 131072;                     // [TOT x 128] = 4194304 floats
    float* Wp   = GH + (size_t)TOT * 128;          // [64 x 128] = 8192
    float* bp   = Wp + 8192;                       // 128

    // -------- conv1 (C=6): fused concat+norm, direct-distance kNN, factored layer-1
    concat_norm_kernel<<<(TOT + 255) / 256, 256, 0, stream>>>(x, pos, f0, nrm, TOT);
    knn6_kernel<<<TOT / 32, 128, 0, stream>>>(f0, nrm, idxb);
    hg6_kernel<<<(TOT * 128) / 256, 256, 0, stream>>>(f0, c1_W1, c1_b1, GH, TOT);
    edgeconv_fact_kernel<<<TOT, 64, 0, stream>>>(GH, idxb,
        c1_g, c1_be, c1_W2, c1_b2, feat + 0, 192);

    // -------- conv2 (C=64): factored layer-1
    norm_kernel<64><<<(TOT + 255) / 256, 256, 0, stream>>>(feat + 0, 192, nrm, TOT);
    knn_tile_kernel<64><<<TOT / 32, 128, 0, stream>>>(feat + 0, 192, nrm, idxb);
    repack_w1_kernel<<<16, 256, 0, stream>>>(c2_W1, c2_b1, Wp, bp);
    gemm_kernel<false><<<dim3(1, TOT / 128), 256, 0, stream>>>(
        feat + 0, 192, Wp, bp, GH, 128, 128, 64);
    edgeconv_fact_kernel<<<TOT, 64, 0, stream>>>(GH, idxb,
        c2_g, c2_be, c2_W2, c2_b2, feat + 64, 192);

    // -------- conv3 (C=64): factored layer-1
    norm_kernel<64><<<(TOT + 255) / 256, 256, 0, stream>>>(feat + 64, 192, nrm, TOT);
    knn_tile_kernel<64><<<TOT / 32, 128, 0, stream>>>(feat + 64, 192, nrm, idxb);
    repack_w1_kernel<<<16, 256, 0, stream>>>(c3_W1, c3_b1, Wp, bp);
    gemm_kernel<false><<<dim3(1, TOT / 128), 256, 0, stream>>>(
        feat + 64, 192, Wp, bp, GH, 128, 128, 64);
    edgeconv_fact_kernel<<<TOT, 64, 0, stream>>>(GH, idxb,
        c3_g, c3_be, c3_W2, c3_b2, feat + 128, 192);

    // -------- head MLP
    for (int mc = 0; mc < TOT; mc += MC) {
        gemm_kernel<true><<<dim3(1024 / 128, MC / 128), 256, 0, stream>>>(
            feat + (size_t)mc * 192, 192, m_W1, m_b1, h1, 1024, 1024, 192);
        gemm_kernel<true><<<dim3(256 / 128, MC / 128), 256, 0, stream>>>(
            h1, 1024, m_W2, m_b2, h2, 256, 256, 1024);
        gemm_kernel<true><<<dim3(128 / 128, MC / 128), 256, 0, stream>>>(
            h2, 256, m_W3, m_b3, h3, 128, 128, 256);
        head_kernel<<<MC / 4, 256, 0, stream>>>(h3, m_W4, m_b4, out + (size_t)mc * 40);
    }
}

// Round 16
// 2129.565 us; speedup vs baseline: 1.9370x; 1.9370x over previous
//
#include <hip/hip_runtime.h>
#include <math.h>

#define KNN 20
#define NPTS 4096
#define NB 8

__device__ __forceinline__ bool lexless(float d1, int i1, float d2, int i2) {
    return d1 < d2 || (d1 == d2 && i1 < i2);
}

// ---------------------------------------------------------------- concat x|pos + squared norm (fused)
__global__ __launch_bounds__(256) void concat_norm_kernel(const float* __restrict__ x,
                                                          const float* __restrict__ pos,
                                                          float* __restrict__ f0,
                                                          float* __restrict__ nrm, int total) {
    int p = blockIdx.x * 256 + threadIdx.x;
    if (p < total) {
        float v0 = x[(size_t)p*3 + 0], v1 = x[(size_t)p*3 + 1], v2 = x[(size_t)p*3 + 2];
        float v3 = pos[(size_t)p*3 + 0], v4 = pos[(size_t)p*3 + 1], v5 = pos[(size_t)p*3 + 2];
        f0[(size_t)p*6 + 0] = v0; f0[(size_t)p*6 + 1] = v1; f0[(size_t)p*6 + 2] = v2;
        f0[(size_t)p*6 + 3] = v3; f0[(size_t)p*6 + 4] = v4; f0[(size_t)p*6 + 5] = v5;
        float s = 0.f;
        s = fmaf(v0, v0, s); s = fmaf(v1, v1, s); s = fmaf(v2, v2, s);
        s = fmaf(v3, v3, s); s = fmaf(v4, v4, s); s = fmaf(v5, v5, s);
        nrm[p] = s;
    }
}

// ---------------------------------------------------------------- squared norms
template<int C>
__global__ __launch_bounds__(256) void norm_kernel(const float* __restrict__ f, int ldf,
                                                   float* __restrict__ norms, int total) {
    int p = blockIdx.x * 256 + threadIdx.x;
    if (p >= total) return;
    const float* fp = f + (size_t)p * ldf;
    float s = 0.f;
    if constexpr ((C & 3) == 0) {
#pragma unroll
        for (int k = 0; k < C; k += 4) {
            float4 v = *(const float4*)(fp + k);
            s = fmaf(v.x, v.x, s); s = fmaf(v.y, v.y, s);
            s = fmaf(v.z, v.z, s); s = fmaf(v.w, v.w, s);
        }
    } else {
#pragma unroll
        for (int k = 0; k < C; ++k) s = fmaf(fp[k], fp[k], s);
    }
    norms[p] = s;
}

// ---- sortable-key top-k machinery -------------------------------------------
// key = (sign-fixed float bits << 32) | idx ; u64 '<' == lexless((d,idx)).
// Internal names chosen to avoid macro variable capture (round-3 lesson).
#define KCHAIN(ck_) do {                                                 \
    unsigned long long kc = (ck_);                                       \
    _Pragma("unroll")                                                    \
    for (int t = 0; t < KNN; ++t) {                                      \
        bool sw = kc < bk[t];                                            \
        unsigned long long nn = sw ? kc : bk[t];                         \
        unsigned long long oo = sw ? bk[t] : kc;                         \
        bk[t] = nn; kc = oo;                                             \
    }                                                                    \
} while (0)

#define PACKK(dv_, jv_, out_) do {                                       \
    unsigned pu = __float_as_uint(dv_);                                  \
    pu = (pu == 0x80000000u) ? 0u : pu;     /* -0 -> +0 */               \
    pu ^= (unsigned)((int)pu >> 31) | 0x80000000u;                       \
    (out_) = ((unsigned long long)pu << 32) | (unsigned)(jv_);           \
} while (0)

// Fast-path push: raw float compare vs cached threshold (superset of the exact
// key test; the chain rejects exactly at flush time). Pending depth 6:
// cadence-4 checks of cnt>=3 -> residual<=2, +4 new <= 6 (holds ACROSS tiles).
#define PUSHF(dv_, jg_) do {                                             \
    if ((dv_) <= thr) {                                                  \
        pd5 = pd4; pj5 = pj4; pd4 = pd3; pj4 = pj3;                      \
        pd3 = pd2; pj3 = pj2; pd2 = pd1; pj2 = pj1;                      \
        pd1 = pd0; pj1 = pj0; pd0 = (dv_); pj0 = (jg_); ++cnt;           \
    }                                                                    \
} while (0)

// Flush: exact u64-key chain insert of pending items, then tighten own float
// threshold from bk[19] and share it per-query via LDS atomicMin.
#define FLUSHF() do {                                                    \
    if (cnt > 0) { unsigned long long k0_; PACKK(pd0, pj0, k0_); KCHAIN(k0_); } \
    if (cnt > 1) { unsigned long long k1_; PACKK(pd1, pj1, k1_); KCHAIN(k1_); } \
    if (cnt > 2) { unsigned long long k2_; PACKK(pd2, pj2, k2_); KCHAIN(k2_); } \
    if (cnt > 3) { unsigned long long k3_; PACKK(pd3, pj3, k3_); KCHAIN(k3_); } \
    if (cnt > 4) { unsigned long long k4_; PACKK(pd4, pj4, k4_); KCHAIN(k4_); } \
    if (cnt > 5) { unsigned long long k5_; PACKK(pd5, pj5, k5_); KCHAIN(k5_); } \
    cnt = 0;                                                             \
    unsigned hu_ = (unsigned)(bk[KNN - 1] >> 32);                        \
    atomicMin(&thrQ[q], hu_);                                            \
    hu_ = (hu_ & 0x80000000u) ? (hu_ ^ 0x80000000u) : ~hu_;              \
    thr = __uint_as_float(hu_);                                          \
} while (0)

#define KMERGE(ptr_) do {                                                \
    const unsigned long long* mp = (ptr_);                               \
    _Pragma("unroll 1")                                                  \
    for (int tm = 0; tm < KNN; ++tm) {                                   \
        unsigned long long mk = mp[tm];                                  \
        if (mk >= bk[KNN - 1]) break;                                    \
        KCHAIN(mk);                                                      \
    }                                                                    \
} while (0)

// sentinel key = pack(+INF, 0xFFFFFFFF)
#define KSENTINEL 0xFF800000FFFFFFFFULL

// ---------------------------------------------------------------- fused tiled kNN (C=64)
// Query-split; 128-thread block owns 32 queries; grid = TOT/32 = 1024 blocks.
// R7 structure. R15 keeper: per-tile forced drain removed (cadence-4 cnt>=3
// ballot bounds pending at 6 across tiles; final drain before merge kept).
template<int C>
__global__ __launch_bounds__(128, 2) void knn_tile_kernel(const float* __restrict__ f, int ldf,
                                                          const float* __restrict__ norms,
                                                          int* __restrict__ idx) {
    const int qb    = blockIdx.x * 32;
    const int b     = qb >> 12;
    const int qloc0 = qb & (NPTS - 1);
    const int tid   = threadIdx.x;
    const int q     = tid & 31;            // query (scan/merge role)
    const int sub   = tid >> 5;            // 0..3 candidate sub-range
    const int tx    = tid & 15;            // candidate quad (GEMM role)
    const int ty    = tid >> 4;            // query quad 0..7 (GEMM role)

    union __align__(16) SM {
        struct {
            float Qs[C][32];
            float Cs[C][64];
            float Ds[32][68];              // row stride 272 B (16B-aligned)
        } a;
        unsigned long long md[32][2 * KNN + 1];   // merge lists (padded stride)
    };
    __shared__ SM sm;
    __shared__ unsigned thrQ[32];          // per-query shared packed threshold

    const float* fb = f + (size_t)b * NPTS * ldf;
    const float* nb = norms + (size_t)b * NPTS;

    if (tid < 32) thrQ[tid] = 0xFFFFFFFFu;

    // ---- stage query tile Qs[k][m] (once)
    if constexpr ((C & 15) == 0) {
        int m = tid >> 2, ko = (tid & 3) * 4;
        const float* src = fb + (size_t)(qloc0 + m) * ldf;
#pragma unroll
        for (int k4 = ko; k4 < C; k4 += 16) {
            float4 v = *(const float4*)(src + k4);
            sm.a.Qs[k4 + 0][m] = v.x; sm.a.Qs[k4 + 1][m] = v.y;
            sm.a.Qs[k4 + 2][m] = v.z; sm.a.Qs[k4 + 3][m] = v.w;
        }
    } else {
        for (int e = tid; e < C * 32; e += 128) {
            int k = e >> 5, m = e & 31;
            sm.a.Qs[k][m] = fb[(size_t)(qloc0 + m) * ldf + k];
        }
    }

    const float4 qnv = *(const float4*)(nb + qloc0 + ty * 4);
    const float qnr[4] = {qnv.x, qnv.y, qnv.z, qnv.w};

    unsigned long long bk[KNN];
#pragma unroll
    for (int t = 0; t < KNN; ++t) bk[t] = KSENTINEL;
    float thr = INFINITY;
    float pd0 = 0.f, pd1 = 0.f, pd2 = 0.f, pd3 = 0.f, pd4 = 0.f, pd5 = 0.f;
    int   pj0 = 0, pj1 = 0, pj2 = 0, pj3 = 0, pj4 = 0, pj5 = 0;
    int   cnt = 0;

    auto stageC = [&](int j0) {
        if constexpr ((C & 7) == 0) {
            int jj = tid >> 1, ko = (tid & 1) * 4;
            const float* src = fb + (size_t)(j0 + jj) * ldf;
#pragma unroll
            for (int k4 = ko; k4 < C; k4 += 8) {
                float4 v = *(const float4*)(src + k4);
                sm.a.Cs[k4 + 0][jj] = v.x; sm.a.Cs[k4 + 1][jj] = v.y;
                sm.a.Cs[k4 + 2][jj] = v.z; sm.a.Cs[k4 + 3][jj] = v.w;
            }
        } else {
            for (int e = tid; e < C * 64; e += 128) {
                int k = e >> 6, j = e & 63;
                sm.a.Cs[k][j] = fb[(size_t)(j0 + j) * ldf + k];
            }
        }
    };

    auto gemmT = [&](int j0) {
        float acc[4][4] = {};
#pragma unroll 8
        for (int kk = 0; kk < C; ++kk) {
            float4 av = *(const float4*)&sm.a.Qs[kk][ty * 4];
            float4 bv = *(const float4*)&sm.a.Cs[kk][tx * 4];
            float a[4] = {av.x, av.y, av.z, av.w};
            float bb[4] = {bv.x, bv.y, bv.z, bv.w};
#pragma unroll
            for (int i = 0; i < 4; ++i)
#pragma unroll
                for (int j = 0; j < 4; ++j) acc[i][j] = fmaf(a[i], bb[j], acc[i][j]);
        }
        const float4 cnv = *(const float4*)(nb + j0 + tx * 4);
#pragma unroll
        for (int i = 0; i < 4; ++i) {
            float4 o;
            o.x = fmaf(-2.0f, acc[i][0], qnr[i] + cnv.x);
            o.y = fmaf(-2.0f, acc[i][1], qnr[i] + cnv.y);
            o.z = fmaf(-2.0f, acc[i][2], qnr[i] + cnv.z);
            o.w = fmaf(-2.0f, acc[i][3], qnr[i] + cnv.w);
            *(float4*)&sm.a.Ds[ty * 4 + i][tx * 4] = o;
        }
    };

    auto scanT = [&](int j0) {
        {
            unsigned su = thrQ[q];
            unsigned hu = (su & 0x80000000u) ? (su ^ 0x80000000u) : ~su;
            thr = fminf(thr, __uint_as_float(hu));
        }
        const int jb = sub * 16;
        const float4 v0 = *(const float4*)&sm.a.Ds[q][jb + 0];
        const float4 v1 = *(const float4*)&sm.a.Ds[q][jb + 4];
        const float4 v2 = *(const float4*)&sm.a.Ds[q][jb + 8];
        const float4 v3 = *(const float4*)&sm.a.Ds[q][jb + 12];
        const int jg = j0 + jb;
        PUSHF(v0.x, jg + 0);  PUSHF(v0.y, jg + 1);
        PUSHF(v0.z, jg + 2);  PUSHF(v0.w, jg + 3);  if (__any(cnt >= 3)) FLUSHF();
        PUSHF(v1.x, jg + 4);  PUSHF(v1.y, jg + 5);
        PUSHF(v1.z, jg + 6);  PUSHF(v1.w, jg + 7);  if (__any(cnt >= 3)) FLUSHF();
        PUSHF(v2.x, jg + 8);  PUSHF(v2.y, jg + 9);
        PUSHF(v2.z, jg + 10); PUSHF(v2.w, jg + 11); if (__any(cnt >= 3)) FLUSHF();
        PUSHF(v3.x, jg + 12); PUSHF(v3.y, jg + 13);
        PUSHF(v3.z, jg + 14); PUSHF(v3.w, jg + 15); if (__any(cnt >= 3)) FLUSHF();
        // no per-tile drain: pending persists across tiles, depth <= 6
    };

    // ---- pipelined main loop: 2 barriers per tile
    stageC(0);
    __syncthreads();
    gemmT(0);
    __syncthreads();
#pragma unroll 1
    for (int t = 1; t < NPTS / 64; ++t) {
        stageC(t * 64);          // writes Cs (gemm(t-1) done reading it)
        scanT((t - 1) * 64);     // reads Ds(t-1)
        __syncthreads();
        gemmT(t * 64);           // reads Cs(t), overwrites Ds
        __syncthreads();
    }
    scanT(NPTS - 64);
    if (__any(cnt > 0)) FLUSHF();   // final drain before merge

    // ---- hierarchical 4 -> 1 merge of sorted lists (per query q)
    __syncthreads();   // all Ds reads done; alias md over a.*
    if (sub >= 2) {
#pragma unroll
        for (int t = 0; t < KNN; ++t) sm.md[q][(sub - 2) * KNN + t] = bk[t];
    }
    __syncthreads();
    if (sub < 2) KMERGE(&sm.md[q][sub * KNN]);
    __syncthreads();
    if (sub == 1) {
#pragma unroll
        for (int t = 0; t < KNN; ++t) sm.md[q][t] = bk[t];
    }
    __syncthreads();
    if (sub == 0) {
        KMERGE(&sm.md[q][0]);
        int* op = idx + (size_t)(qb + q) * KNN;
#pragma unroll
        for (int t = 0; t < KNN; ++t) op[t] = (int)bk[t];
    }
}

// ---------------------------------------------------------------- specialized kNN for C=6
// (128, 2) — NOT (128, 4): R11 lesson (64-VGPR cap spilled bk[20]).
__global__ __launch_bounds__(128, 2) void knn6_kernel(const float* __restrict__ f,
                                                      const float* __restrict__ norms,
                                                      int* __restrict__ idx) {
    const int qb    = blockIdx.x * 32;
    const int b     = qb >> 12;
    const int qloc0 = qb & (NPTS - 1);
    const int tid   = threadIdx.x;
    const int q     = tid & 31;
    const int sub   = tid >> 5;

    __shared__ __align__(16) float Cs[2][64][8];
    __shared__ unsigned long long md[32][2 * KNN + 1];
    __shared__ unsigned thrQ[32];

    const float* fb = f + (size_t)b * NPTS * 6;
    const float* nb = norms + (size_t)b * NPTS;

    if (tid < 32) thrQ[tid] = 0xFFFFFFFFu;

    float fir[6];
    {
        const float* qsrc = fb + (size_t)(qloc0 + q) * 6;
#pragma unroll
        for (int k = 0; k < 6; ++k) fir[k] = qsrc[k];
    }
    const float qn = nb[qloc0 + q];

    unsigned long long bk[KNN];
#pragma unroll
    for (int t = 0; t < KNN; ++t) bk[t] = KSENTINEL;
    float thr = INFINITY;
    float pd0 = 0.f, pd1 = 0.f, pd2 = 0.f, pd3 = 0.f, pd4 = 0.f, pd5 = 0.f;
    int   pj0 = 0, pj1 = 0, pj2 = 0, pj3 = 0, pj4 = 0, pj5 = 0;
    int   cnt = 0;

    auto stage6 = [&](int j0, int s) {
#pragma unroll
        for (int e = tid; e < 512; e += 128) {
            int j = e >> 3, k = e & 7;
            float v = 0.f;
            if (k < 6)       v = fb[(size_t)(j0 + j) * 6 + k];
            else if (k == 6) v = nb[j0 + j];
            Cs[s][j][k] = v;
        }
    };

    auto scan6 = [&](int j0, int s) {
        {
            unsigned su = thrQ[q];
            unsigned hu = (su & 0x80000000u) ? (su ^ 0x80000000u) : ~su;
            thr = fminf(thr, __uint_as_float(hu));
        }
        const int jb = sub * 16;
#pragma unroll
        for (int jj = 0; jj < 16; ++jj) {
            const float4 c0 = *(const float4*)&Cs[s][jb + jj][0];
            const float4 c1 = *(const float4*)&Cs[s][jb + jj][4];
            float dot = 0.f;
            dot = fmaf(fir[0], c0.x, dot);
            dot = fmaf(fir[1], c0.y, dot);
            dot = fmaf(fir[2], c0.z, dot);
            dot = fmaf(fir[3], c0.w, dot);
            dot = fmaf(fir[4], c1.x, dot);
            dot = fmaf(fir[5], c1.y, dot);
            float d = fmaf(-2.0f, dot, qn + c1.z);
            PUSHF(d, j0 + jb + jj);
            if ((jj & 3) == 3) { if (__any(cnt >= 3)) FLUSHF(); }
        }
        // no per-tile drain
    };

    stage6(0, 0);
    __syncthreads();
#pragma unroll 1
    for (int t = 0; t < NPTS / 64; ++t) {
        const int cur = t & 1;
        if (t + 1 < NPTS / 64) stage6((t + 1) * 64, cur ^ 1);
        scan6(t * 64, cur);
        __syncthreads();
    }
    if (__any(cnt > 0)) FLUSHF();   // final drain

    if (sub >= 2) {
#pragma unroll
        for (int t = 0; t < KNN; ++t) md[q][(sub - 2) * KNN + t] = bk[t];
    }
    __syncthreads();
    if (sub < 2) KMERGE(&md[q][sub * KNN]);
    __syncthreads();
    if (sub == 1) {
#pragma unroll
        for (int t = 0; t < KNN; ++t) md[q][t] = bk[t];
    }
    __syncthreads();
    if (sub == 0) {
        KMERGE(&md[q][0]);
        int* op = idx + (size_t)(qb + q) * KNN;
#pragma unroll
        for (int t = 0; t < KNN; ++t) op[t] = (int)bk[t];
    }
}

// ---------------------------------------------------------------- H|G for conv1 (C=6): tiny K=6 dense layer
__global__ __launch_bounds__(256) void hg6_kernel(const float* __restrict__ f0,
                                                  const float* __restrict__ W1,
                                                  const float* __restrict__ b1,
                                                  float* __restrict__ GH, int total) {
    int t = blockIdx.x * 256 + threadIdx.x;
    if (t >= total * 128) return;
    int p  = t >> 7;
    int cc = t & 127;
    int c  = cc & 63;
    bool isG = cc >= 64;
    const float* fp = f0 + (size_t)p * 6;
    const float* Wb = W1 + (isG ? 6 * 64 : 0);
    float acc = isG ? 0.f : b1[c];
#pragma unroll
    for (int k = 0; k < 6; ++k) acc = fmaf(fp[k], Wb[k * 64 + c], acc);
    GH[(size_t)p * 128 + cc] = acc;
}

// ---------------------------------------------------------------- repack W1 -> [64 x 128] (W1a | W1b), bias' = (b1 | 0)
__global__ __launch_bounds__(256) void repack_w1_kernel(const float* __restrict__ W1,
                                                        const float* __restrict__ b1,
                                                        float* __restrict__ Wp,
                                                        float* __restrict__ bp) {
    int t = blockIdx.x * 256 + threadIdx.x;
    if (t < 64 * 64) {
        int k = t >> 6, c = t & 63;
        Wp[k * 128 + c]      = W1[k * 64 + c];          // W1a
        Wp[k * 128 + 64 + c] = W1[(64 + k) * 64 + c];   // W1b
    }
    if (t < 128) bp[t] = (t < 64) ? b1[t] : 0.f;
}

// ---------------------------------------------------------------- factored EdgeConv: layer1 = adds on precomputed GH
__global__ __launch_bounds__(64) void edgeconv_fact_kernel(
    const float* __restrict__ GH,          // [TOT x 128]: [H | G]
    const int* __restrict__ idx,
    const float* __restrict__ g,  const float* __restrict__ be,
    const float* __restrict__ W2, const float* __restrict__ b2,
    float* __restrict__ out, int ldo) {
    const int p = blockIdx.x;
    const int b = p >> 12;
    const int c = threadIdx.x;   // channel 0..63
    __shared__ __align__(16) float h1_s[KNN][64];
    __shared__ int nidx[KNN];
    if (c < KNN) nidx[c] = idx[(size_t)p * KNN + c];
    const float H = GH[(size_t)p * 128 + c];
    const float G = GH[(size_t)p * 128 + 64 + c];
    const float hb = H - G;                       // (H_i - G_i)
    const float bn_s = (float)(1.0 / sqrt(1.0 + 1e-5));
    const float bnscale = g[c] * bn_s;
    const float bec = be[c];
    const float* GHb = GH + (size_t)b * NPTS * 128 + 64;  // G part, batch base
    __syncthreads();
#pragma unroll
    for (int j = 0; j < KNN; ++j) {
        float gj = GHb[(size_t)nidx[j] * 128 + c];
        h1_s[j][c] = fmaxf(fmaf(hb + gj, bnscale, bec), 0.f);
    }
    __syncthreads();

    float acc2[KNN];
    float b2c = b2[c];
#pragma unroll
    for (int j = 0; j < KNN; ++j) acc2[j] = b2c;
#pragma unroll
    for (int k = 0; k < 64; k += 4) {
        float w0 = W2[(k + 0) * 64 + c];
        float w1 = W2[(k + 1) * 64 + c];
        float w2 = W2[(k + 2) * 64 + c];
        float w3 = W2[(k + 3) * 64 + c];
#pragma unroll
        for (int j = 0; j < KNN; ++j) {
            float4 v = *(const float4*)&h1_s[j][k];
            acc2[j] = fmaf(v.x, w0, acc2[j]);
            acc2[j] = fmaf(v.y, w1, acc2[j]);
            acc2[j] = fmaf(v.z, w2, acc2[j]);
            acc2[j] = fmaf(v.w, w3, acc2[j]);
        }
    }
    float m = acc2[0];
#pragma unroll
    for (int j = 1; j < KNN; ++j) m = fmaxf(m, acc2[j]);
    out[(size_t)p * ldo + c] = m;
}

// ---------------------------------------------------------------- tiled fp32 GEMM: C = act(A@W + b)
// 128x128x16 tile, 256 threads, 8x8 micro-tile (1 B/FMA LDS intensity).
// R14 single-buffered form. R15's register-prefetch double-buffer REVERTED:
// acc[8][8] (64 VGPR) + 16 prefetch regs tipped the allocator over the
// (256,2) cliff -> accumulator spilled to scratch (VGPR=128, 5.7 GB scratch
// traffic/dispatch, 6x slowdown). This kernel family sits ~20 VGPRs from its
// occupancy cliff; register-resident prefetch schemes are a dead lever.
template<bool RELU>
__global__ __launch_bounds__(256, 2) void gemm_kernel(
    const float* __restrict__ A, int lda,
    const float* __restrict__ W,          // [K, N] row-major
    const float* __restrict__ bias,
    float* __restrict__ Cc, int ldc,
    int N, int K) {
    const int BM = 128, BN = 128, BK = 16;
    __shared__ __align__(16) float As[16][128 + 4];
    __shared__ __align__(16) float Bs[16][128 + 4];
    const int bm = blockIdx.y * BM;
    const int bn = blockIdx.x * BN;
    const int tid = threadIdx.x;
    const int tx = tid & 15, ty = tid >> 4;
    float acc[8][8] = {};
    for (int k0 = 0; k0 < K; k0 += BK) {
        {   // A tile: 128 rows x 16 k; thread loads 2 float4 (rows r, r+64)
            int r = tid >> 2;
            int kq = (tid & 3) * 4;
#pragma unroll
            for (int h = 0; h < 2; ++h) {
                int rr = r + h * 64;
                float4 v = *(const float4*)(A + (size_t)(bm + rr) * lda + k0 + kq);
                As[kq + 0][rr] = v.x; As[kq + 1][rr] = v.y;
                As[kq + 2][rr] = v.z; As[kq + 3][rr] = v.w;
            }
        }
        {   // W tile: 16 k-rows x 128 cols; thread loads 2 float4 contiguous
            int kk = tid >> 4;
            int n8 = (tid & 15) * 8;
            float4 v0 = *(const float4*)(W + (size_t)(k0 + kk) * N + bn + n8);
            float4 v1 = *(const float4*)(W + (size_t)(k0 + kk) * N + bn + n8 + 4);
            *(float4*)&Bs[kk][n8] = v0;
            *(float4*)&Bs[kk][n8 + 4] = v1;
        }
        __syncthreads();
#pragma unroll
        for (int kk = 0; kk < BK; ++kk) {
            float4 a0 = *(const float4*)&As[kk][ty * 8];
            float4 a1 = *(const float4*)&As[kk][ty * 8 + 4];
            float4 b0 = *(const float4*)&Bs[kk][tx * 8];
            float4 b1 = *(const float4*)&Bs[kk][tx * 8 + 4];
            float a[8] = {a0.x, a0.y, a0.z, a0.w, a1.x, a1.y, a1.z, a1.w};
            float bb[8] = {b0.x, b0.y, b0.z, b0.w, b1.x, b1.y, b1.z, b1.w};
#pragma unroll
            for (int i = 0; i < 8; ++i)
#pragma unroll
                for (int j = 0; j < 8; ++j) acc[i][j] = fmaf(a[i], bb[j], acc[i][j]);
        }
        __syncthreads();
    }
    const float4 bi0 = *(const float4*)(bias + bn + tx * 8);
    const float4 bi1 = *(const float4*)(bias + bn + tx * 8 + 4);
    const float bb[8] = {bi0.x, bi0.y, bi0.z, bi0.w, bi1.x, bi1.y, bi1.z, bi1.w};
#pragma unroll
    for (int i = 0; i < 8; ++i) {
        int m = bm + ty * 8 + i;
        float4 o0, o1;
        o0.x = acc[i][0] + bb[0]; o0.y = acc[i][1] + bb[1];
        o0.z = acc[i][2] + bb[2]; o0.w = acc[i][3] + bb[3];
        o1.x = acc[i][4] + bb[4]; o1.y = acc[i][5] + bb[5];
        o1.z = acc[i][6] + bb[6]; o1.w = acc[i][7] + bb[7];
        if (RELU) {
            o0.x = fmaxf(o0.x, 0.f); o0.y = fmaxf(o0.y, 0.f);
            o0.z = fmaxf(o0.z, 0.f); o0.w = fmaxf(o0.w, 0.f);
            o1.x = fmaxf(o1.x, 0.f); o1.y = fmaxf(o1.y, 0.f);
            o1.z = fmaxf(o1.z, 0.f); o1.w = fmaxf(o1.w, 0.f);
        }
        *(float4*)(Cc + (size_t)m * ldc + bn + tx * 8) = o0;
        *(float4*)(Cc + (size_t)m * ldc + bn + tx * 8 + 4) = o1;
    }
}

// ---------------------------------------------------------------- final layer (K=128 -> 40) + log_softmax
// 256 threads = 4 waves = 4 points; W4 + h-rows staged in LDS.
__global__ __launch_bounds__(256) void head_kernel(const float* __restrict__ h3,
                                                   const float* __restrict__ W4,
                                                   const float* __restrict__ b4,
                                                   float* __restrict__ out) {
    __shared__ float W4s[128 * 40];
    __shared__ float hps[4][128];
    const int tid  = threadIdx.x;
    const int w    = tid >> 6;
    const int lane = tid & 63;
    const int p    = blockIdx.x * 4 + w;     // chunk-local point
    for (int e = tid; e < 128 * 40; e += 256) W4s[e] = W4[e];
    if (lane < 32)
        *(float4*)&hps[w][lane * 4] = *(const float4*)(h3 + (size_t)p * 128 + lane * 4);
    __syncthreads();
    float v = -INFINITY;
    if (lane < 40) {
        float acc = b4[lane];
#pragma unroll
        for (int k = 0; k < 128; ++k) acc = fmaf(hps[w][k], W4s[k * 40 + lane], acc);
        v = acc;
    }
    float mx = v;
#pragma unroll
    for (int s = 1; s < 64; s <<= 1) mx = fmaxf(mx, __shfl_xor(mx, s));
    float e = (lane < 40) ? expf(v - mx) : 0.0f;
    float se = e;
#pragma unroll
    for (int s = 1; s < 64; s <<= 1) se += __shfl_xor(se, s);
    if (lane < 40) out[(size_t)p * 40 + lane] = v - mx - logf(se);
}

// ----------------------------------------------------------------
extern "C" void kernel_launch(void* const* d_in, const int* in_sizes, int n_in,
                              void* d_out, int out_size, void* d_ws, size_t ws_size,
                              hipStream_t stream) {
    (void)in_sizes; (void)n_in; (void)out_size;
    const float* x     = (const float*)d_in[0];
    const float* pos   = (const float*)d_in[1];
    const float* c1_W1 = (const float*)d_in[2];
    const float* c1_b1 = (const float*)d_in[3];
    const float* c1_g  = (const float*)d_in[4];
    const float* c1_be = (const float*)d_in[5];
    const float* c1_W2 = (const float*)d_in[6];
    const float* c1_b2 = (const float*)d_in[7];
    const float* c2_W1 = (const float*)d_in[8];
    const float* c2_b1 = (const float*)d_in[9];
    const float* c2_g  = (const float*)d_in[10];
    const float* c2_be = (const float*)d_in[11];
    const float* c2_W2 = (const float*)d_in[12];
    const float* c2_b2 = (const float*)d_in[13];
    const float* c3_W1 = (const float*)d_in[14];
    const float* c3_b1 = (const float*)d_in[15];
    const float* c3_g  = (const float*)d_in[16];
    const float* c3_be = (const float*)d_in[17];
    const float* c3_W2 = (const float*)d_in[18];
    const float* c3_b2 = (const float*)d_in[19];
    const float* m_W1  = (const float*)d_in[20];
    const float* m_b1  = (const float*)d_in[21];
    const float* m_W2  = (const float*)d_in[22];
    const float* m_b2  = (const float*)d_in[23];
    const float* m_W3  = (const float*)d_in[24];
    const float* m_b3  = (const float*)d_in[25];
    const float* m_W4  = (const float*)d_in[26];
    const float* m_b4  = (const float*)d_in[27];
    float* out = (float*)d_out;

    const int TOT = NB * NPTS;  // 32768

    // workspace layout (floats):
    float* ws   = (float*)d_ws;
    float* f0   = ws;                              // 196608
    int*   idxb = (int*)(ws + 196608);             // 655360 ints
    float* feat = ws + 196608 + 655360;            // 6291456  [32768 x 192]

    const size_t basef  = 196608 + 655360 + 6291456;
    const size_t availf = ws_size / 4;
    int MC = 4096;
    if (availf >= basef + (size_t)32768 * 1408) MC = 32768;
    else if (availf >= basef + (size_t)16384 * 1408) MC = 16384;
    else if (availf >= basef + (size_t)8192 * 1408) MC = 8192;

    float* h1   = feat + 6291456;                  // [MC x 1024]
    float* h2   = h1 + (size_t)MC * 1024;          // [MC x 256]
    float* h3   = h2 + (size_t)MC * 256;           // [MC x 128]
    // conv-phase scratch (MLP region is dead then). Region size >= 5.77M floats.
    float* nrm  = h1;                              // 32768 floats
    float* GH   = h1 + 131072;                     // [TOT x 128] = 4194304 floats
    float* Wp   = GH + (size_t)TOT * 128;          // [64 x 128] = 8192
    float* bp   = Wp + 8192;                       // 128

    // -------- conv1 (C=6): fused concat+norm, direct-distance kNN, factored layer-1
    concat_norm_kernel<<<(TOT + 255) / 256, 256, 0, stream>>>(x, pos, f0, nrm, TOT);
    knn6_kernel<<<TOT / 32, 128, 0, stream>>>(f0, nrm, idxb);
    hg6_kernel<<<(TOT * 128) / 256, 256, 0, stream>>>(f0, c1_W1, c1_b1, GH, TOT);
    edgeconv_fact_kernel<<<TOT, 64, 0, stream>>>(GH, idxb,
        c1_g, c1_be, c1_W2, c1_b2, feat + 0, 192);

    // -------- conv2 (C=64): factored layer-1
    norm_kernel<64><<<(TOT + 255) / 256, 256, 0, stream>>>(feat + 0, 192, nrm, TOT);
    knn_tile_kernel<64><<<TOT / 32, 128, 0, stream>>>(feat + 0, 192, nrm, idxb);
    repack_w1_kernel<<<16, 256, 0, stream>>>(c2_W1, c2_b1, Wp, bp);
    gemm_kernel<false><<<dim3(1, TOT / 128), 256, 0, stream>>>(
        feat + 0, 192, Wp, bp, GH, 128, 128, 64);
    edgeconv_fact_kernel<<<TOT, 64, 0, stream>>>(GH, idxb,
        c2_g, c2_be, c2_W2, c2_b2, feat + 64, 192);

    // -------- conv3 (C=64): factored layer-1
    norm_kernel<64><<<(TOT + 255) / 256, 256, 0, stream>>>(feat + 64, 192, nrm, TOT);
    knn_tile_kernel<64><<<TOT / 32, 128, 0, stream>>>(feat + 64, 192, nrm, idxb);
    repack_w1_kernel<<<16, 256, 0, stream>>>(c3_W1, c3_b1, Wp, bp);
    gemm_kernel<false><<<dim3(1, TOT / 128), 256, 0, stream>>>(
        feat + 64, 192, Wp, bp, GH, 128, 128, 64);
    edgeconv_fact_kernel<<<TOT, 64, 0, stream>>>(GH, idxb,
        c3_g, c3_be, c3_W2, c3_b2, feat + 128, 192);

    // -------- head MLP
    for (int mc = 0; mc < TOT; mc += MC) {
        gemm_kernel<true><<<dim3(1024 / 128, MC / 128), 256, 0, stream>>>(
            feat + (size_t)mc * 192, 192, m_W1, m_b1, h1, 1024, 1024, 192);
        gemm_kernel<true><<<dim3(256 / 128, MC / 128), 256, 0, stream>>>(
            h1, 1024, m_W2, m_b2, h2, 256, 256, 1024);
        gemm_kernel<true><<<dim3(128 / 128, MC / 128), 256, 0, stream>>>(
            h2, 256, m_W3, m_b3, h3, 128, 128, 256);
        head_kernel<<<MC / 4, 256, 0, stream>>>(h3, m_W4, m_b4, out + (size_t)mc * 40);
    }
}

// Round 17
// 2082.122 us; speedup vs baseline: 1.9811x; 1.0228x over previous
//
#include <hip/hip_runtime.h>
#include <math.h>

#define KNN 20
#define NPTS 4096
#define NB 8

__device__ __forceinline__ bool lexless(float d1, int i1, float d2, int i2) {
    return d1 < d2 || (d1 == d2 && i1 < i2);
}

// ---------------------------------------------------------------- concat x|pos + squared norm (fused)
__global__ __launch_bounds__(256) void concat_norm_kernel(const float* __restrict__ x,
                                                          const float* __restrict__ pos,
                                                          float* __restrict__ f0,
                                                          float* __restrict__ nrm, int total) {
    int p = blockIdx.x * 256 + threadIdx.x;
    if (p < total) {
        float v0 = x[(size_t)p*3 + 0], v1 = x[(size_t)p*3 + 1], v2 = x[(size_t)p*3 + 2];
        float v3 = pos[(size_t)p*3 + 0], v4 = pos[(size_t)p*3 + 1], v5 = pos[(size_t)p*3 + 2];
        f0[(size_t)p*6 + 0] = v0; f0[(size_t)p*6 + 1] = v1; f0[(size_t)p*6 + 2] = v2;
        f0[(size_t)p*6 + 3] = v3; f0[(size_t)p*6 + 4] = v4; f0[(size_t)p*6 + 5] = v5;
        float s = 0.f;
        s = fmaf(v0, v0, s); s = fmaf(v1, v1, s); s = fmaf(v2, v2, s);
        s = fmaf(v3, v3, s); s = fmaf(v4, v4, s); s = fmaf(v5, v5, s);
        nrm[p] = s;
    }
}

// ---------------------------------------------------------------- squared norms
template<int C>
__global__ __launch_bounds__(256) void norm_kernel(const float* __restrict__ f, int ldf,
                                                   float* __restrict__ norms, int total) {
    int p = blockIdx.x * 256 + threadIdx.x;
    if (p >= total) return;
    const float* fp = f + (size_t)p * ldf;
    float s = 0.f;
    if constexpr ((C & 3) == 0) {
#pragma unroll
        for (int k = 0; k < C; k += 4) {
            float4 v = *(const float4*)(fp + k);
            s = fmaf(v.x, v.x, s); s = fmaf(v.y, v.y, s);
            s = fmaf(v.z, v.z, s); s = fmaf(v.w, v.w, s);
        }
    } else {
#pragma unroll
        for (int k = 0; k < C; ++k) s = fmaf(fp[k], fp[k], s);
    }
    norms[p] = s;
}

// ---- sortable-key top-k machinery -------------------------------------------
// key = (sign-fixed float bits << 32) | idx ; u64 '<' == lexless((d,idx)).
// Internal names chosen to avoid macro variable capture (round-3 lesson).
#define KCHAIN(ck_) do {                                                 \
    unsigned long long kc = (ck_);                                       \
    _Pragma("unroll")                                                    \
    for (int t = 0; t < KNN; ++t) {                                      \
        bool sw = kc < bk[t];                                            \
        unsigned long long nn = sw ? kc : bk[t];                         \
        unsigned long long oo = sw ? bk[t] : kc;                         \
        bk[t] = nn; kc = oo;                                             \
    }                                                                    \
} while (0)

#define PACKK(dv_, jv_, out_) do {                                       \
    unsigned pu = __float_as_uint(dv_);                                  \
    pu = (pu == 0x80000000u) ? 0u : pu;     /* -0 -> +0 */               \
    pu ^= (unsigned)((int)pu >> 31) | 0x80000000u;                       \
    (out_) = ((unsigned long long)pu << 32) | (unsigned)(jv_);           \
} while (0)

// Fast-path push: raw float compare vs cached threshold (superset of the exact
// key test; the chain rejects exactly at flush time). Pending depth 6:
// cadence-4 checks of cnt>=3 -> residual<=2, +4 new <= 6 (holds ACROSS tiles).
#define PUSHF(dv_, jg_) do {                                             \
    if ((dv_) <= thr) {                                                  \
        pd5 = pd4; pj5 = pj4; pd4 = pd3; pj4 = pj3;                      \
        pd3 = pd2; pj3 = pj2; pd2 = pd1; pj2 = pj1;                      \
        pd1 = pd0; pj1 = pj0; pd0 = (dv_); pj0 = (jg_); ++cnt;           \
    }                                                                    \
} while (0)

// Flush: exact u64-key chain insert of pending items, then tighten own float
// threshold from bk[19] and share it per-query via LDS atomicMin.
#define FLUSHF() do {                                                    \
    if (cnt > 0) { unsigned long long k0_; PACKK(pd0, pj0, k0_); KCHAIN(k0_); } \
    if (cnt > 1) { unsigned long long k1_; PACKK(pd1, pj1, k1_); KCHAIN(k1_); } \
    if (cnt > 2) { unsigned long long k2_; PACKK(pd2, pj2, k2_); KCHAIN(k2_); } \
    if (cnt > 3) { unsigned long long k3_; PACKK(pd3, pj3, k3_); KCHAIN(k3_); } \
    if (cnt > 4) { unsigned long long k4_; PACKK(pd4, pj4, k4_); KCHAIN(k4_); } \
    if (cnt > 5) { unsigned long long k5_; PACKK(pd5, pj5, k5_); KCHAIN(k5_); } \
    cnt = 0;                                                             \
    unsigned hu_ = (unsigned)(bk[KNN - 1] >> 32);                        \
    atomicMin(&thrQ[q], hu_);                                            \
    hu_ = (hu_ & 0x80000000u) ? (hu_ ^ 0x80000000u) : ~hu_;              \
    thr = __uint_as_float(hu_);                                          \
} while (0)

#define KMERGE(ptr_) do {                                                \
    const unsigned long long* mp = (ptr_);                               \
    _Pragma("unroll 1")                                                  \
    for (int tm = 0; tm < KNN; ++tm) {                                   \
        unsigned long long mk = mp[tm];                                  \
        if (mk >= bk[KNN - 1]) break;                                    \
        KCHAIN(mk);                                                      \
    }                                                                    \
} while (0)

// sentinel key = pack(+INF, 0xFFFFFFFF)
#define KSENTINEL 0xFF800000FFFFFFFFULL

// ---------------------------------------------------------------- fused tiled kNN (C=64)
// Query-split; 128-thread block owns 32 queries; grid = TOT/32 = 1024 blocks.
// R7 structure (parked at ~560 us after 7 variants within +-2%).
template<int C>
__global__ __launch_bounds__(128, 2) void knn_tile_kernel(const float* __restrict__ f, int ldf,
                                                          const float* __restrict__ norms,
                                                          int* __restrict__ idx) {
    const int qb    = blockIdx.x * 32;
    const int b     = qb >> 12;
    const int qloc0 = qb & (NPTS - 1);
    const int tid   = threadIdx.x;
    const int q     = tid & 31;            // query (scan/merge role)
    const int sub   = tid >> 5;            // 0..3 candidate sub-range
    const int tx    = tid & 15;            // candidate quad (GEMM role)
    const int ty    = tid >> 4;            // query quad 0..7 (GEMM role)

    union __align__(16) SM {
        struct {
            float Qs[C][32];
            float Cs[C][64];
            float Ds[32][68];              // row stride 272 B (16B-aligned)
        } a;
        unsigned long long md[32][2 * KNN + 1];   // merge lists (padded stride)
    };
    __shared__ SM sm;
    __shared__ unsigned thrQ[32];          // per-query shared packed threshold

    const float* fb = f + (size_t)b * NPTS * ldf;
    const float* nb = norms + (size_t)b * NPTS;

    if (tid < 32) thrQ[tid] = 0xFFFFFFFFu;

    // ---- stage query tile Qs[k][m] (once)
    if constexpr ((C & 15) == 0) {
        int m = tid >> 2, ko = (tid & 3) * 4;
        const float* src = fb + (size_t)(qloc0 + m) * ldf;
#pragma unroll
        for (int k4 = ko; k4 < C; k4 += 16) {
            float4 v = *(const float4*)(src + k4);
            sm.a.Qs[k4 + 0][m] = v.x; sm.a.Qs[k4 + 1][m] = v.y;
            sm.a.Qs[k4 + 2][m] = v.z; sm.a.Qs[k4 + 3][m] = v.w;
        }
    } else {
        for (int e = tid; e < C * 32; e += 128) {
            int k = e >> 5, m = e & 31;
            sm.a.Qs[k][m] = fb[(size_t)(qloc0 + m) * ldf + k];
        }
    }

    const float4 qnv = *(const float4*)(nb + qloc0 + ty * 4);
    const float qnr[4] = {qnv.x, qnv.y, qnv.z, qnv.w};

    unsigned long long bk[KNN];
#pragma unroll
    for (int t = 0; t < KNN; ++t) bk[t] = KSENTINEL;
    float thr = INFINITY;
    float pd0 = 0.f, pd1 = 0.f, pd2 = 0.f, pd3 = 0.f, pd4 = 0.f, pd5 = 0.f;
    int   pj0 = 0, pj1 = 0, pj2 = 0, pj3 = 0, pj4 = 0, pj5 = 0;
    int   cnt = 0;

    auto stageC = [&](int j0) {
        if constexpr ((C & 7) == 0) {
            int jj = tid >> 1, ko = (tid & 1) * 4;
            const float* src = fb + (size_t)(j0 + jj) * ldf;
#pragma unroll
            for (int k4 = ko; k4 < C; k4 += 8) {
                float4 v = *(const float4*)(src + k4);
                sm.a.Cs[k4 + 0][jj] = v.x; sm.a.Cs[k4 + 1][jj] = v.y;
                sm.a.Cs[k4 + 2][jj] = v.z; sm.a.Cs[k4 + 3][jj] = v.w;
            }
        } else {
            for (int e = tid; e < C * 64; e += 128) {
                int k = e >> 6, j = e & 63;
                sm.a.Cs[k][j] = fb[(size_t)(j0 + j) * ldf + k];
            }
        }
    };

    auto gemmT = [&](int j0) {
        float acc[4][4] = {};
#pragma unroll 8
        for (int kk = 0; kk < C; ++kk) {
            float4 av = *(const float4*)&sm.a.Qs[kk][ty * 4];
            float4 bv = *(const float4*)&sm.a.Cs[kk][tx * 4];
            float a[4] = {av.x, av.y, av.z, av.w};
            float bb[4] = {bv.x, bv.y, bv.z, bv.w};
#pragma unroll
            for (int i = 0; i < 4; ++i)
#pragma unroll
                for (int j = 0; j < 4; ++j) acc[i][j] = fmaf(a[i], bb[j], acc[i][j]);
        }
        const float4 cnv = *(const float4*)(nb + j0 + tx * 4);
#pragma unroll
        for (int i = 0; i < 4; ++i) {
            float4 o;
            o.x = fmaf(-2.0f, acc[i][0], qnr[i] + cnv.x);
            o.y = fmaf(-2.0f, acc[i][1], qnr[i] + cnv.y);
            o.z = fmaf(-2.0f, acc[i][2], qnr[i] + cnv.z);
            o.w = fmaf(-2.0f, acc[i][3], qnr[i] + cnv.w);
            *(float4*)&sm.a.Ds[ty * 4 + i][tx * 4] = o;
        }
    };

    auto scanT = [&](int j0) {
        {
            unsigned su = thrQ[q];
            unsigned hu = (su & 0x80000000u) ? (su ^ 0x80000000u) : ~su;
            thr = fminf(thr, __uint_as_float(hu));
        }
        const int jb = sub * 16;
        const float4 v0 = *(const float4*)&sm.a.Ds[q][jb + 0];
        const float4 v1 = *(const float4*)&sm.a.Ds[q][jb + 4];
        const float4 v2 = *(const float4*)&sm.a.Ds[q][jb + 8];
        const float4 v3 = *(const float4*)&sm.a.Ds[q][jb + 12];
        const int jg = j0 + jb;
        PUSHF(v0.x, jg + 0);  PUSHF(v0.y, jg + 1);
        PUSHF(v0.z, jg + 2);  PUSHF(v0.w, jg + 3);  if (__any(cnt >= 3)) FLUSHF();
        PUSHF(v1.x, jg + 4);  PUSHF(v1.y, jg + 5);
        PUSHF(v1.z, jg + 6);  PUSHF(v1.w, jg + 7);  if (__any(cnt >= 3)) FLUSHF();
        PUSHF(v2.x, jg + 8);  PUSHF(v2.y, jg + 9);
        PUSHF(v2.z, jg + 10); PUSHF(v2.w, jg + 11); if (__any(cnt >= 3)) FLUSHF();
        PUSHF(v3.x, jg + 12); PUSHF(v3.y, jg + 13);
        PUSHF(v3.z, jg + 14); PUSHF(v3.w, jg + 15); if (__any(cnt >= 3)) FLUSHF();
        // no per-tile drain: pending persists across tiles, depth <= 6
    };

    // ---- pipelined main loop: 2 barriers per tile
    stageC(0);
    __syncthreads();
    gemmT(0);
    __syncthreads();
#pragma unroll 1
    for (int t = 1; t < NPTS / 64; ++t) {
        stageC(t * 64);          // writes Cs (gemm(t-1) done reading it)
        scanT((t - 1) * 64);     // reads Ds(t-1)
        __syncthreads();
        gemmT(t * 64);           // reads Cs(t), overwrites Ds
        __syncthreads();
    }
    scanT(NPTS - 64);
    if (__any(cnt > 0)) FLUSHF();   // final drain before merge

    // ---- hierarchical 4 -> 1 merge of sorted lists (per query q)
    __syncthreads();   // all Ds reads done; alias md over a.*
    if (sub >= 2) {
#pragma unroll
        for (int t = 0; t < KNN; ++t) sm.md[q][(sub - 2) * KNN + t] = bk[t];
    }
    __syncthreads();
    if (sub < 2) KMERGE(&sm.md[q][sub * KNN]);
    __syncthreads();
    if (sub == 1) {
#pragma unroll
        for (int t = 0; t < KNN; ++t) sm.md[q][t] = bk[t];
    }
    __syncthreads();
    if (sub == 0) {
        KMERGE(&sm.md[q][0]);
        int* op = idx + (size_t)(qb + q) * KNN;
#pragma unroll
        for (int t = 0; t < KNN; ++t) op[t] = (int)bk[t];
    }
}

// ---------------------------------------------------------------- specialized kNN for C=6
// (128, 2) — NOT (128, 4): R11 lesson (64-VGPR cap spilled bk[20]).
__global__ __launch_bounds__(128, 2) void knn6_kernel(const float* __restrict__ f,
                                                      const float* __restrict__ norms,
                                                      int* __restrict__ idx) {
    const int qb    = blockIdx.x * 32;
    const int b     = qb >> 12;
    const int qloc0 = qb & (NPTS - 1);
    const int tid   = threadIdx.x;
    const int q     = tid & 31;
    const int sub   = tid >> 5;

    __shared__ __align__(16) float Cs[2][64][8];
    __shared__ unsigned long long md[32][2 * KNN + 1];
    __shared__ unsigned thrQ[32];

    const float* fb = f + (size_t)b * NPTS * 6;
    const float* nb = norms + (size_t)b * NPTS;

    if (tid < 32) thrQ[tid] = 0xFFFFFFFFu;

    float fir[6];
    {
        const float* qsrc = fb + (size_t)(qloc0 + q) * 6;
#pragma unroll
        for (int k = 0; k < 6; ++k) fir[k] = qsrc[k];
    }
    const float qn = nb[qloc0 + q];

    unsigned long long bk[KNN];
#pragma unroll
    for (int t = 0; t < KNN; ++t) bk[t] = KSENTINEL;
    float thr = INFINITY;
    float pd0 = 0.f, pd1 = 0.f, pd2 = 0.f, pd3 = 0.f, pd4 = 0.f, pd5 = 0.f;
    int   pj0 = 0, pj1 = 0, pj2 = 0, pj3 = 0, pj4 = 0, pj5 = 0;
    int   cnt = 0;

    auto stage6 = [&](int j0, int s) {
#pragma unroll
        for (int e = tid; e < 512; e += 128) {
            int j = e >> 3, k = e & 7;
            float v = 0.f;
            if (k < 6)       v = fb[(size_t)(j0 + j) * 6 + k];
            else if (k == 6) v = nb[j0 + j];
            Cs[s][j][k] = v;
        }
    };

    auto scan6 = [&](int j0, int s) {
        {
            unsigned su = thrQ[q];
            unsigned hu = (su & 0x80000000u) ? (su ^ 0x80000000u) : ~su;
            thr = fminf(thr, __uint_as_float(hu));
        }
        const int jb = sub * 16;
#pragma unroll
        for (int jj = 0; jj < 16; ++jj) {
            const float4 c0 = *(const float4*)&Cs[s][jb + jj][0];
            const float4 c1 = *(const float4*)&Cs[s][jb + jj][4];
            float dot = 0.f;
            dot = fmaf(fir[0], c0.x, dot);
            dot = fmaf(fir[1], c0.y, dot);
            dot = fmaf(fir[2], c0.z, dot);
            dot = fmaf(fir[3], c0.w, dot);
            dot = fmaf(fir[4], c1.x, dot);
            dot = fmaf(fir[5], c1.y, dot);
            float d = fmaf(-2.0f, dot, qn + c1.z);
            PUSHF(d, j0 + jb + jj);
            if ((jj & 3) == 3) { if (__any(cnt >= 3)) FLUSHF(); }
        }
        // no per-tile drain
    };

    stage6(0, 0);
    __syncthreads();
#pragma unroll 1
    for (int t = 0; t < NPTS / 64; ++t) {
        const int cur = t & 1;
        if (t + 1 < NPTS / 64) stage6((t + 1) * 64, cur ^ 1);
        scan6(t * 64, cur);
        __syncthreads();
    }
    if (__any(cnt > 0)) FLUSHF();   // final drain

    if (sub >= 2) {
#pragma unroll
        for (int t = 0; t < KNN; ++t) md[q][(sub - 2) * KNN + t] = bk[t];
    }
    __syncthreads();
    if (sub < 2) KMERGE(&md[q][sub * KNN]);
    __syncthreads();
    if (sub == 1) {
#pragma unroll
        for (int t = 0; t < KNN; ++t) md[q][t] = bk[t];
    }
    __syncthreads();
    if (sub == 0) {
        KMERGE(&md[q][0]);
        int* op = idx + (size_t)(qb + q) * KNN;
#pragma unroll
        for (int t = 0; t < KNN; ++t) op[t] = (int)bk[t];
    }
}

// ---------------------------------------------------------------- H|G for conv1 (C=6): tiny K=6 dense layer
__global__ __launch_bounds__(256) void hg6_kernel(const float* __restrict__ f0,
                                                  const float* __restrict__ W1,
                                                  const float* __restrict__ b1,
                                                  float* __restrict__ GH, int total) {
    int t = blockIdx.x * 256 + threadIdx.x;
    if (t >= total * 128) return;
    int p  = t >> 7;
    int cc = t & 127;
    int c  = cc & 63;
    bool isG = cc >= 64;
    const float* fp = f0 + (size_t)p * 6;
    const float* Wb = W1 + (isG ? 6 * 64 : 0);
    float acc = isG ? 0.f : b1[c];
#pragma unroll
    for (int k = 0; k < 6; ++k) acc = fmaf(fp[k], Wb[k * 64 + c], acc);
    GH[(size_t)p * 128 + cc] = acc;
}

// ---------------------------------------------------------------- repack W1 -> [64 x 128] (W1a | W1b), bias' = (b1 | 0)
__global__ __launch_bounds__(256) void repack_w1_kernel(const float* __restrict__ W1,
                                                        const float* __restrict__ b1,
                                                        float* __restrict__ Wp,
                                                        float* __restrict__ bp) {
    int t = blockIdx.x * 256 + threadIdx.x;
    if (t < 64 * 64) {
        int k = t >> 6, c = t & 63;
        Wp[k * 128 + c]      = W1[k * 64 + c];          // W1a
        Wp[k * 128 + 64 + c] = W1[(64 + k) * 64 + c];   // W1b
    }
    if (t < 128) bp[t] = (t < 64) ? b1[t] : 0.f;
}

// ---------------------------------------------------------------- factored EdgeConv: layer1 = adds on precomputed GH
__global__ __launch_bounds__(64) void edgeconv_fact_kernel(
    const float* __restrict__ GH,          // [TOT x 128]: [H | G]
    const int* __restrict__ idx,
    const float* __restrict__ g,  const float* __restrict__ be,
    const float* __restrict__ W2, const float* __restrict__ b2,
    float* __restrict__ out, int ldo) {
    const int p = blockIdx.x;
    const int b = p >> 12;
    const int c = threadIdx.x;   // channel 0..63
    __shared__ __align__(16) float h1_s[KNN][64];
    __shared__ int nidx[KNN];
    if (c < KNN) nidx[c] = idx[(size_t)p * KNN + c];
    const float H = GH[(size_t)p * 128 + c];
    const float G = GH[(size_t)p * 128 + 64 + c];
    const float hb = H - G;                       // (H_i - G_i)
    const float bn_s = (float)(1.0 / sqrt(1.0 + 1e-5));
    const float bnscale = g[c] * bn_s;
    const float bec = be[c];
    const float* GHb = GH + (size_t)b * NPTS * 128 + 64;  // G part, batch base
    __syncthreads();
#pragma unroll
    for (int j = 0; j < KNN; ++j) {
        float gj = GHb[(size_t)nidx[j] * 128 + c];
        h1_s[j][c] = fmaxf(fmaf(hb + gj, bnscale, bec), 0.f);
    }
    __syncthreads();

    float acc2[KNN];
    float b2c = b2[c];
#pragma unroll
    for (int j = 0; j < KNN; ++j) acc2[j] = b2c;
#pragma unroll
    for (int k = 0; k < 64; k += 4) {
        float w0 = W2[(k + 0) * 64 + c];
        float w1 = W2[(k + 1) * 64 + c];
        float w2 = W2[(k + 2) * 64 + c];
        float w3 = W2[(k + 3) * 64 + c];
#pragma unroll
        for (int j = 0; j < KNN; ++j) {
            float4 v = *(const float4*)&h1_s[j][k];
            acc2[j] = fmaf(v.x, w0, acc2[j]);
            acc2[j] = fmaf(v.y, w1, acc2[j]);
            acc2[j] = fmaf(v.z, w2, acc2[j]);
            acc2[j] = fmaf(v.w, w3, acc2[j]);
        }
    }
    float m = acc2[0];
#pragma unroll
    for (int j = 1; j < KNN; ++j) m = fmaxf(m, acc2[j]);
    out[(size_t)p * ldo + c] = m;
}

// ---------------------------------------------------------------- tiled fp32 GEMM: C = act(A@W + b)
// 128x128xBK32 tile, 256 threads, 8x8 micro-tile (1 B/FMA LDS intensity).
// R17: BK 16->32 halves barrier count (GEMM2: 128 -> 64 barriers) at the same
// LDS intensity. Staging regs (8 x float4) die BEFORE the FMA loop — unlike
// R15's prefetch (which kept values live across compute and spilled acc).
// K must be a multiple of 32 (all call sites: 192/1024/256/64).
// fmaf order stays k-ascending -> bitwise-identical outputs.
template<bool RELU>
__global__ __launch_bounds__(256, 2) void gemm_kernel(
    const float* __restrict__ A, int lda,
    const float* __restrict__ W,          // [K, N] row-major
    const float* __restrict__ bias,
    float* __restrict__ Cc, int ldc,
    int N, int K) {
    const int BK = 32;
    __shared__ __align__(16) float As[32][128 + 4];
    __shared__ __align__(16) float Bs[32][128 + 4];
    const int bm = blockIdx.y * 128;
    const int bn = blockIdx.x * 128;
    const int tid = threadIdx.x;
    const int tx = tid & 15, ty = tid >> 4;
    float acc[8][8] = {};
    for (int k0 = 0; k0 < K; k0 += BK) {
        {   // A tile: 128 rows x 32 k; thread loads 4 float4 (rows r+32h, k-quad kq)
            int r = tid >> 3;
            int kq = (tid & 7) * 4;
#pragma unroll
            for (int h = 0; h < 4; ++h) {
                int rr = r + h * 32;
                float4 v = *(const float4*)(A + (size_t)(bm + rr) * lda + k0 + kq);
                As[kq + 0][rr] = v.x; As[kq + 1][rr] = v.y;
                As[kq + 2][rr] = v.z; As[kq + 3][rr] = v.w;
            }
        }
        {   // W tile: 32 k-rows x 128 cols; thread loads 2x2 float4
            int kk = tid >> 4;
            int n8 = (tid & 15) * 8;
#pragma unroll
            for (int h = 0; h < 2; ++h) {
                int kkk = kk + h * 16;
                float4 v0 = *(const float4*)(W + (size_t)(k0 + kkk) * N + bn + n8);
                float4 v1 = *(const float4*)(W + (size_t)(k0 + kkk) * N + bn + n8 + 4);
                *(float4*)&Bs[kkk][n8] = v0;
                *(float4*)&Bs[kkk][n8 + 4] = v1;
            }
        }
        __syncthreads();
#pragma unroll
        for (int kk = 0; kk < BK; ++kk) {
            float4 a0 = *(const float4*)&As[kk][ty * 8];
            float4 a1 = *(const float4*)&As[kk][ty * 8 + 4];
            float4 b0 = *(const float4*)&Bs[kk][tx * 8];
            float4 b1 = *(const float4*)&Bs[kk][tx * 8 + 4];
            float a[8] = {a0.x, a0.y, a0.z, a0.w, a1.x, a1.y, a1.z, a1.w};
            float bb[8] = {b0.x, b0.y, b0.z, b0.w, b1.x, b1.y, b1.z, b1.w};
#pragma unroll
            for (int i = 0; i < 8; ++i)
#pragma unroll
                for (int j = 0; j < 8; ++j) acc[i][j] = fmaf(a[i], bb[j], acc[i][j]);
        }
        __syncthreads();
    }
    const float4 bi0 = *(const float4*)(bias + bn + tx * 8);
    const float4 bi1 = *(const float4*)(bias + bn + tx * 8 + 4);
    const float bb[8] = {bi0.x, bi0.y, bi0.z, bi0.w, bi1.x, bi1.y, bi1.z, bi1.w};
#pragma unroll
    for (int i = 0; i < 8; ++i) {
        int m = bm + ty * 8 + i;
        float4 o0, o1;
        o0.x = acc[i][0] + bb[0]; o0.y = acc[i][1] + bb[1];
        o0.z = acc[i][2] + bb[2]; o0.w = acc[i][3] + bb[3];
        o1.x = acc[i][4] + bb[4]; o1.y = acc[i][5] + bb[5];
        o1.z = acc[i][6] + bb[6]; o1.w = acc[i][7] + bb[7];
        if (RELU) {
            o0.x = fmaxf(o0.x, 0.f); o0.y = fmaxf(o0.y, 0.f);
            o0.z = fmaxf(o0.z, 0.f); o0.w = fmaxf(o0.w, 0.f);
            o1.x = fmaxf(o1.x, 0.f); o1.y = fmaxf(o1.y, 0.f);
            o1.z = fmaxf(o1.z, 0.f); o1.w = fmaxf(o1.w, 0.f);
        }
        *(float4*)(Cc + (size_t)m * ldc + bn + tx * 8) = o0;
        *(float4*)(Cc + (size_t)m * ldc + bn + tx * 8 + 4) = o1;
    }
}

// ---------------------------------------------------------------- final layer (K=128 -> 40) + log_softmax
// 256 threads = 4 waves = 4 points; W4 + h-rows staged in LDS.
__global__ __launch_bounds__(256) void head_kernel(const float* __restrict__ h3,
                                                   const float* __restrict__ W4,
                                                   const float* __restrict__ b4,
                                                   float* __restrict__ out) {
    __shared__ float W4s[128 * 40];
    __shared__ float hps[4][128];
    const int tid  = threadIdx.x;
    const int w    = tid >> 6;
    const int lane = tid & 63;
    const int p    = blockIdx.x * 4 + w;     // chunk-local point
    for (int e = tid; e < 128 * 40; e += 256) W4s[e] = W4[e];
    if (lane < 32)
        *(float4*)&hps[w][lane * 4] = *(const float4*)(h3 + (size_t)p * 128 + lane * 4);
    __syncthreads();
    float v = -INFINITY;
    if (lane < 40) {
        float acc = b4[lane];
#pragma unroll
        for (int k = 0; k < 128; ++k) acc = fmaf(hps[w][k], W4s[k * 40 + lane], acc);
        v = acc;
    }
    float mx = v;
#pragma unroll
    for (int s = 1; s < 64; s <<= 1) mx = fmaxf(mx, __shfl_xor(mx, s));
    float e = (lane < 40) ? expf(v - mx) : 0.0f;
    float se = e;
#pragma unroll
    for (int s = 1; s < 64; s <<= 1) se += __shfl_xor(se, s);
    if (lane < 40) out[(size_t)p * 40 + lane] = v - mx - logf(se);
}

// ----------------------------------------------------------------
extern "C" void kernel_launch(void* const* d_in, const int* in_sizes, int n_in,
                              void* d_out, int out_size, void* d_ws, size_t ws_size,
                              hipStream_t stream) {
    (void)in_sizes; (void)n_in; (void)out_size;
    const float* x     = (const float*)d_in[0];
    const float* pos   = (const float*)d_in[1];
    const float* c1_W1 = (const float*)d_in[2];
    const float* c1_b1 = (const float*)d_in[3];
    const float* c1_g  = (const float*)d_in[4];
    const float* c1_be = (const float*)d_in[5];
    const float* c1_W2 = (const float*)d_in[6];
    const float* c1_b2 = (const float*)d_in[7];
    const float* c2_W1 = (const float*)d_in[8];
    const float* c2_b1 = (const float*)d_in[9];
    const float* c2_g  = (const float*)d_in[10];
    const float* c2_be = (const float*)d_in[11];
    const float* c2_W2 = (const float*)d_in[12];
    const float* c2_b2 = (const float*)d_in[13];
    const float* c3_W1 = (const float*)d_in[14];
    const float* c3_b1 = (const float*)d_in[15];
    const float* c3_g  = (const float*)d_in[16];
    const float* c3_be = (const float*)d_in[17];
    const float* c3_W2 = (const float*)d_in[18];
    const float* c3_b2 = (const float*)d_in[19];
    const float* m_W1  = (const float*)d_in[20];
    const float* m_b1  = (const float*)d_in[21];
    const float* m_W2  = (const float*)d_in[22];
    const float* m_b2  = (const float*)d_in[23];
    const float* m_W3  = (const float*)d_in[24];
    const float* m_b3  = (const float*)d_in[25];
    const float* m_W4  = (const float*)d_in[26];
    const float* m_b4  = (const float*)d_in[27];
    float* out = (float*)d_out;

    const int TOT = NB * NPTS;  // 32768

    // workspace layout (floats):
    float* ws   = (float*)d_ws;
    float* f0   = ws;                              // 196608
    int*   idxb = (int*)(ws + 196608);             // 655360 ints
    float* feat = ws + 196608 + 655360;            // 6291456  [32768 x 192]

    const size_t basef  = 196608 + 655360 + 6291456;
    const size_t availf = ws_size / 4;
    int MC = 4096;
    if (availf >= basef + (size_t)32768 * 1408) MC = 32768;
    else if (availf >= basef + (size_t)16384 * 1408) MC = 16384;
    else if (availf >= basef + (size_t)8192 * 1408) MC = 8192;

    float* h1   = feat + 6291456;                  // [MC x 1024]
    float* h2   = h1 + (size_t)MC * 1024;          // [MC x 256]
    float* h3   = h2 + (size_t)MC * 256;           // [MC x 128]
    // conv-phase scratch (MLP region is dead then). Region size >= 5.77M floats.
    float* nrm  = h1;                              // 32768 floats
    float* GH   = h1 + 131072;                     // [TOT x 128] = 4194304 floats
    float* Wp   = GH + (size_t)TOT * 128;          // [64 x 128] = 8192
    float* bp   = Wp + 8192;                       // 128

    // -------- conv1 (C=6): fused concat+norm, direct-distance kNN, factored layer-1
    concat_norm_kernel<<<(TOT + 255) / 256, 256, 0, stream>>>(x, pos, f0, nrm, TOT);
    knn6_kernel<<<TOT / 32, 128, 0, stream>>>(f0, nrm, idxb);
    hg6_kernel<<<(TOT * 128) / 256, 256, 0, stream>>>(f0, c1_W1, c1_b1, GH, TOT);
    edgeconv_fact_kernel<<<TOT, 64, 0, stream>>>(GH, idxb,
        c1_g, c1_be, c1_W2, c1_b2, feat + 0, 192);

    // -------- conv2 (C=64): factored layer-1
    norm_kernel<64><<<(TOT + 255) / 256, 256, 0, stream>>>(feat + 0, 192, nrm, TOT);
    knn_tile_kernel<64><<<TOT / 32, 128, 0, stream>>>(feat + 0, 192, nrm, idxb);
    repack_w1_kernel<<<16, 256, 0, stream>>>(c2_W1, c2_b1, Wp, bp);
    gemm_kernel<false><<<dim3(1, TOT / 128), 256, 0, stream>>>(
        feat + 0, 192, Wp, bp, GH, 128, 128, 64);
    edgeconv_fact_kernel<<<TOT, 64, 0, stream>>>(GH, idxb,
        c2_g, c2_be, c2_W2, c2_b2, feat + 64, 192);

    // -------- conv3 (C=64): factored layer-1
    norm_kernel<64><<<(TOT + 255) / 256, 256, 0, stream>>>(feat + 64, 192, nrm, TOT);
    knn_tile_kernel<64><<<TOT / 32, 128, 0, stream>>>(feat + 64, 192, nrm, idxb);
    repack_w1_kernel<<<16, 256, 0, stream>>>(c3_W1, c3_b1, Wp, bp);
    gemm_kernel<false><<<dim3(1, TOT / 128), 256, 0, stream>>>(
        feat + 64, 192, Wp, bp, GH, 128, 128, 64);
    edgeconv_fact_kernel<<<TOT, 64, 0, stream>>>(GH, idxb,
        c3_g, c3_be, c3_W2, c3_b2, feat + 128, 192);

    // -------- head MLP
    for (int mc = 0; mc < TOT; mc += MC) {
        gemm_kernel<true><<<dim3(1024 / 128, MC / 128), 256, 0, stream>>>(
            feat + (size_t)mc * 192, 192, m_W1, m_b1, h1, 1024, 1024, 192);
        gemm_kernel<true><<<dim3(256 / 128, MC / 128), 256, 0, stream>>>(
            h1, 1024, m_W2, m_b2, h2, 256, 256, 1024);
        gemm_kernel<true><<<dim3(128 / 128, MC / 128), 256, 0, stream>>>(
            h2, 256, m_W3, m_b3, h3, 128, 128, 256);
        head_kernel<<<MC / 4, 256, 0, stream>>>(h3, m_W4, m_b4, out + (size_t)mc * 40);
    }
}